// Round 5
// baseline (1626.115 us; speedup 1.0000x reference)
//
#include <hip/hip_runtime.h>

// ---------------- problem constants ----------------
constexpr int N_   = 512;
constexpr int PIX  = 1024;    // 32*32
constexpr int L_   = 1024;
constexpr int F_   = 32768;   // 32*32*32
constexpr int H_   = 512;
constexpr float IC_ = 1.0f / (float)(512 * 1024);   // 1/(N*PIX), BN count

__device__ __forceinline__ float lrelu(float t) { return t >= 0.f ? t : 0.01f * t; }

using frag  = __attribute__((ext_vector_type(8))) short;   // 8 bf16 (4 VGPRs)
using f32x4 = __attribute__((ext_vector_type(4))) float;   // MFMA accum
using s4    = __attribute__((ext_vector_type(4))) short;   // ds_write_b64 pack

// Non-draining barrier: orders LDS (lgkmcnt) but lets register-destined
// global loads stay in flight across the barrier.
#define BAR() do {                                              \
    asm volatile("s_waitcnt lgkmcnt(0)" ::: "memory");          \
    __builtin_amdgcn_s_barrier();                               \
    asm volatile("" ::: "memory");                              \
} while (0)

// split v = hi + lo, both bf16 (truncation; lo captures the tail exactly,
// dropped lo*lo term ~2^-16 relative)
__device__ __forceinline__ void split_bf16(float v, short& hi, short& lo) {
    const unsigned b = __float_as_uint(v);
    hi = (short)(b >> 16);
    const float hf = __uint_as_float(b & 0xFFFF0000u);
    lo = (short)(__float_as_uint(v - hf) >> 16);
}

// two ds_read_b64 -> one 8-bf16 fragment (stride-72B LDS rows can't align b128)
__device__ __forceinline__ frag ld2(const short* p) {
    union { frag f; struct { unsigned long long a, b; } u; } x;
    x.u.a = *(const unsigned long long*)(p);
    x.u.b = *(const unsigned long long*)(p + 4);
    return x.f;
}

// ======== weight pre-split: OIHW fp32 -> fragment-ordered bf16 hi/lo ========
// All 6 big-conv layers in ONE launch: grid (72, 6), layer = blockIdx.y.
__global__ __launch_bounds__(256) void wsplit6_kernel(
    const float* __restrict__ w0, const float* __restrict__ w1,
    const float* __restrict__ w2, const float* __restrict__ w3,
    const float* __restrict__ w4, const float* __restrict__ w5,
    short* __restrict__ hi, short* __restrict__ lo)
{
    const int layer = blockIdx.y;
    const float* W = layer == 0 ? w0 : layer == 1 ? w1 : layer == 2 ? w2 :
                     layer == 3 ? w3 : layer == 4 ? w4 : w5;
    const int CIN  = (layer == 1 || layer == 3) ? 64 : 32;
    const int NCOT = (layer == 1 || layer == 3) ? 2 : 4;
    const int idx = blockIdx.x * 256 + threadIdx.x;       // 72*256 = 18432 exact
    const int j    = idx & 7;
    const int lane = (idx >> 3) & 63;
    const int q    = lane >> 4, lm = lane & 15;
    const int blk  = idx >> 9;
    const int cot  = blk % NCOT;
    const int rest = blk / NCOT;
    const int pos  = rest % 9;
    const int cc   = rest / 9;
    const int co = cot * 16 + lm;
    const int ci = cc * 32 + q * 8 + j;
    short h, l;
    split_bf16(W[((size_t)co * CIN + ci) * 9 + pos], h, l);
    hi[layer * 18432 + idx] = h;
    lo[layer * 18432 + idx] = l;
}

// ======== conv 3x3 SAME via implicit-GEMM MFMA (split-bf16, 3-pass) =========
// Round-5: 4-row tiles. Block: one image, 4 output rows (128 px), ALL Cout.
// Plane 6x34 = 204 staged px <= 256 threads -> single-coverage staging (no
// dual-index path), LDS 29.4 KB -> 4-5 blocks/CU, launch_bounds(256,4).
template<int CIN, int COUT, bool BN_IN>
__global__ __launch_bounds__(256, 4) void conv_mfma(
    const float* __restrict__ in, const short* __restrict__ wh,
    const short* __restrict__ wl, const float* __restrict__ bias,
    float* __restrict__ out, const float* __restrict__ stats_in,
    float* __restrict__ stats_out)
{
    constexpr int NCOT = COUT / 16;
    constexpr int NCH  = CIN / 32;
    constexpr int STR  = 36;              // shorts per staged pixel
    constexpr int PLsh = 204 * STR;       // plane: 6 rows x 34 cols
    __shared__ __align__(16) short hiL[PLsh];
    __shared__ __align__(16) short loL[PLsh];       // ~29.4 KB
    __shared__ float red[2 * COUT];
    __shared__ float bnm[64], bni[64];
    const int tid  = threadIdx.x;
    const int n    = blockIdx.x >> 3;
    const int y0   = (blockIdx.x & 7) << 2;
    const int lane = tid & 63;
    const int wv   = tid >> 6;
    const int lm   = lane & 15;
    const int q    = lane >> 4;

    if (tid < 2 * COUT) red[tid] = 0.f;
    if (BN_IN && tid < CIN) {
        const float m  = stats_in[tid] * IC_;
        const float qq = stats_in[CIN + tid] * IC_;
        bnm[tid] = m;
        bni[tid] = rsqrtf(qq - m * m + 1e-5f);
    }
    __syncthreads();

    f32x4 acc[NCOT][2];
#pragma unroll
    for (int t = 0; t < NCOT; ++t)
#pragma unroll
        for (int pt = 0; pt < 2; ++pt) acc[t][pt] = {0.f, 0.f, 0.f, 0.f};

    // staging coords: 204 staged px, one per thread (tid < 204)
    const int rs0 = tid / 34, cs0 = tid % 34;
    const int gr0 = y0 - 1 + rs0, gc0 = cs0 - 1;
    const bool act = tid < 204;
    const bool ok0 = act && ((unsigned)gr0 < 32u) && ((unsigned)gc0 < 32u);
    const int  po0 = gr0 * 32 + gc0;

    const float* inb = in + ((size_t)n * CIN << 10);

    // weight fragment double-buffer (static register sets — no runtime index)
    frag ahA[NCOT], alA[NCOT], ahB[NCOT], alB[NCOT];

    auto LDW = [&](frag (&dh)[NCOT], frag (&dl)[NCOT], int posAbs) {
#pragma unroll
        for (int t = 0; t < NCOT; ++t) {
            const size_t wb = (size_t)((posAbs * NCOT + t) * 512 + lane * 8);
            dh[t] = *(const frag*)&wh[wb];
            dl[t] = *(const frag*)&wl[wb];
        }
    };

    auto COMPUTE = [&](int pos, frag (&fh)[NCOT], frag (&fl)[NCOT]) {
        const int ky = pos / 3, kx = pos - ky * 3;
        __builtin_amdgcn_s_setprio(1);
#pragma unroll
        for (int pt = 0; pt < 2; ++pt) {
            const int ptile = wv * 2 + pt;
            const int row = ptile >> 1;
            const int col = ((ptile & 1) << 4) + lm;
            const int loff = ((row + ky) * 34 + col + kx) * STR + q * 8;
            const frag bh = ld2(&hiL[loff]);
            const frag bl = ld2(&loL[loff]);
#pragma unroll
            for (int t = 0; t < NCOT; ++t) {
                acc[t][pt] = __builtin_amdgcn_mfma_f32_16x16x32_bf16(
                    fh[t], bh, acc[t][pt], 0, 0, 0);
                acc[t][pt] = __builtin_amdgcn_mfma_f32_16x16x32_bf16(
                    fh[t], bl, acc[t][pt], 0, 0, 0);
                acc[t][pt] = __builtin_amdgcn_mfma_f32_16x16x32_bf16(
                    fl[t], bh, acc[t][pt], 0, 0, 0);
            }
        }
        __builtin_amdgcn_s_setprio(0);
    };

#pragma unroll 1
    for (int cc = 0; cc < NCH; ++cc) {
        if (cc) BAR();                    // previous chunk's reads done

        // prefetch pos-0 weights of this chunk; flies under the staging phase
        LDW(ahA, alA, cc * 9 + 0);

        // ---- staging: one px per thread, 8-channel batches ----
#pragma unroll 1
        for (int cb = 0; cb < 32; cb += 8) {
            float v0r[8];
#pragma unroll
            for (int u = 0; u < 8; ++u) {
                const int cg = cc * 32 + cb + u;
                v0r[u] = ok0 ? inb[((size_t)cg << 10) + po0] : 0.f;
            }
            if (act) {
#pragma unroll
                for (int u4 = 0; u4 < 8; u4 += 4) {
                    s4 h0v, l0v;
#pragma unroll
                    for (int e = 0; e < 4; ++e) {
                        const int ci = cb + u4 + e;
                        const int cg = cc * 32 + ci;
                        float v0 = v0r[u4 + e];
                        if (BN_IN && ok0) v0 = lrelu((v0 - bnm[cg]) * bni[cg]);
                        short h, l;
                        split_bf16(v0, h, l);
                        h0v[e] = h; l0v[e] = l;
                    }
                    *(s4*)&hiL[tid * STR + cb + u4] = h0v;
                    *(s4*)&loL[tid * STR + cb + u4] = l0v;
                }
            }
        }
        BAR();

        // ---- 9 positions, weights double-buffered (A holds pos, B pos+1) ---
#pragma unroll 1
        for (int pos = 0; pos < 8; pos += 2) {
            LDW(ahB, alB, cc * 9 + pos + 1);   // prefetch pos+1
            COMPUTE(pos, ahA, alA);            // consume pos (already landed)
            LDW(ahA, alA, cc * 9 + pos + 2);   // prefetch pos+2 (max 8)
            COMPUTE(pos + 1, ahB, alB);        // consume pos+1
        }
        COMPUTE(8, ahA, alA);                  // tail: pos 8
    }

    // ---- epilogue: bias, store raw, per-channel stats ----
    // C/D: col(n=px)=lane&15, row(m=co within tile)=q*4+reg
    float* ob = out + ((size_t)n * COUT << 10);
#pragma unroll
    for (int t = 0; t < NCOT; ++t) {
#pragma unroll
        for (int r = 0; r < 4; ++r) {
            const int co = t * 16 + q * 4 + r;
            const float b = bias[co];
            float s = 0.f, sq = 0.f;
#pragma unroll
            for (int pt = 0; pt < 2; ++pt) {
                const int ptile = wv * 2 + pt;
                const float v = acc[t][pt][r] + b;
                ob[((size_t)co << 10) + (y0 << 5) + (ptile << 4) + lm] = v;
                s += v; sq += v * v;
            }
#pragma unroll
            for (int off = 8; off > 0; off >>= 1) {
                s  += __shfl_down(s, off, 64);
                sq += __shfl_down(sq, off, 64);
            }
            if (lm == 0) {
                atomicAdd(&red[co], s);
                atomicAdd(&red[COUT + co], sq);
            }
        }
    }
    __syncthreads();
    if (tid < 2 * COUT) atomicAdd(&stats_out[tid], red[tid]);
}

// ================= conv 3x3 VALU — conv1 & dec-conv3 only ===
template<int CIN, int COPB, bool BN_IN>
__global__ __launch_bounds__(256) void conv3x3(
    const float* __restrict__ in, const float* __restrict__ w,
    const float* __restrict__ bias, float* __restrict__ out,
    const float* __restrict__ stats_in, float* __restrict__ stats_out,
    int Cout)
{
    constexpr int CT = (CIN < 4) ? CIN : 4;
    __shared__ float tile[CT * PIX];
    __shared__ float red[2 * COPB];
    const int groups = Cout / COPB;
    const int n   = blockIdx.x / groups;
    const int co0 = (blockIdx.x % groups) * COPB;
    const int tid = threadIdx.x;
    const int x   = tid & 31;
    const int y0  = (tid >> 5) * 4;

    float acc[COPB][4];
#pragma unroll
    for (int c = 0; c < COPB; ++c)
#pragma unroll
        for (int j = 0; j < 4; ++j) acc[c][j] = 0.f;

    const float* inbase = in + (size_t)n * CIN * PIX;

#pragma unroll 1
    for (int s0 = 0; s0 < CIN; s0 += CT) {
        __syncthreads();
#pragma unroll
        for (int s = 0; s < CT; ++s) {
            float4 v = ((const float4*)(inbase + (size_t)(s0 + s) * PIX))[tid];
            if (BN_IN) {
                const int c = s0 + s;
                const float m   = stats_in[c] * IC_;
                const float q   = stats_in[CIN + c] * IC_;
                const float inv = rsqrtf(q - m * m + 1e-5f);
                v.x = lrelu((v.x - m) * inv);
                v.y = lrelu((v.y - m) * inv);
                v.z = lrelu((v.z - m) * inv);
                v.w = lrelu((v.w - m) * inv);
            }
            ((float4*)tile)[s * 256 + tid] = v;
        }
        __syncthreads();
#pragma unroll 2
        for (int s = 0; s < CT; ++s) {
            const int ci = s0 + s;
            const float* tp = tile + s * PIX;
            float r[6][3];
#pragma unroll
            for (int ry = 0; ry < 6; ++ry) {
                const int yy = y0 + ry - 1;
                const bool yok = (unsigned)yy < 32u;
#pragma unroll
                for (int cx = 0; cx < 3; ++cx) {
                    const int xx = x + cx - 1;
                    const bool ok = yok && ((unsigned)xx < 32u);
                    r[ry][cx] = ok ? tp[yy * 32 + xx] : 0.f;
                }
            }
#pragma unroll
            for (int c = 0; c < COPB; ++c) {
                const float* wp = w + ((size_t)(co0 + c) * CIN + ci) * 9;
#pragma unroll
                for (int ky = 0; ky < 3; ++ky)
#pragma unroll
                    for (int kx = 0; kx < 3; ++kx) {
                        const float wv = wp[ky * 3 + kx];
#pragma unroll
                        for (int j = 0; j < 4; ++j)
                            acc[c][j] += r[ky + j][kx] * wv;
                    }
            }
        }
    }

    if (tid < 2 * COPB) red[tid] = 0.f;
    __syncthreads();
#pragma unroll
    for (int c = 0; c < COPB; ++c) {
        const float b = bias[co0 + c];
        float* ob = out + (((size_t)n * Cout + co0 + c) << 10);
        float s = 0.f, q = 0.f;
#pragma unroll
        for (int j = 0; j < 4; ++j) {
            const float v = acc[c][j] + b;
            ob[(y0 + j) * 32 + x] = v;
            s += v; q += v * v;
        }
#pragma unroll
        for (int off = 32; off > 0; off >>= 1) {
            s += __shfl_down(s, off, 64);
            q += __shfl_down(q, off, 64);
        }
        if ((tid & 63) == 0) {
            atomicAdd(&red[c], s);
            atomicAdd(&red[COPB + c], q);
        }
    }
    __syncthreads();
    if (tid < COPB)
        atomicAdd(&stats_out[co0 + tid], red[tid]);
    else if (tid < 2 * COPB)
        atomicAdd(&stats_out[Cout + co0 + tid - COPB], red[tid]);
}

// ======== split-bf16 MFMA GEMM: C += A(MxK) * B(NxK)^T =====
// Round-5: double-buffered LDS, ONE non-draining barrier per K-step.
// Iter s: MFMA(step s-1 from buf[(s-1)&1]) || stage(step s into buf[s&1])
// || issue loads(step s+1). BN hoisted block-uniform (kchunk=2048 on BN path).
template<bool BN_A>
__global__ __launch_bounds__(256) void gemm_mfma(
    const float* __restrict__ A0, const float* __restrict__ A1,
    const float* __restrict__ B0, const float* __restrict__ B1,
    float* __restrict__ C0, float* __restrict__ C1,
    int K, int Nh, int kchunk, int xph,
    const float* __restrict__ bnstats, int Cin)
{
    __shared__ short AhL[8192], AlL[8192], BhL[8192], BlL[8192];  // 64 KB
    const int tid  = threadIdx.x;
    const int head = blockIdx.x / xph;
    const int n0   = (blockIdx.x % xph) * 128;
    const int m0   = blockIdx.y * 128;
    const float* A = head ? A1 : A0;
    const float* B = head ? B1 : B0;
    float*       C = head ? C1 : C0;
    const int k0 = blockIdx.z * kchunk;

    const int lane = tid & 63;
    const int wv   = tid >> 6;
    const int wm   = wv & 1;
    const int wn   = wv >> 1;
    const int lm   = lane & 15;
    const int q    = lane >> 4;

    const int srow = tid >> 1;
    const int smt  = srow >> 4;
    const int slm  = srow & 15;
    const int sq0  = (tid & 1) * 2;
    const int ks   = (tid & 1) * 16;

    // block-uniform BN: kchunk=2048 on BN path -> channels c0, c0+1
    float bnm0 = 0.f, bni0 = 1.f, bnm1 = 0.f, bni1 = 1.f;
    if (BN_A) {
        const int c0 = k0 >> 10;
        bnm0 = bnstats[c0] * IC_;
        const float q0 = bnstats[Cin + c0] * IC_;
        bni0 = rsqrtf(q0 - bnm0 * bnm0 + 1e-5f);
        const int c1 = (c0 + 1 < Cin) ? c0 + 1 : c0;
        bnm1 = bnstats[c1] * IC_;
        const float q1 = bnstats[Cin + c1] * IC_;
        bni1 = rsqrtf(q1 - bnm1 * bnm1 + 1e-5f);
    }

    f32x4 acc[4][4];
#pragma unroll
    for (int i = 0; i < 4; ++i)
#pragma unroll
        for (int j = 0; j < 4; ++j) acc[i][j] = {0.f, 0.f, 0.f, 0.f};

    auto cv8 = [](float4 u, float4 w2, frag& h, frag& l) {
        const float v[8] = {u.x, u.y, u.z, u.w, w2.x, w2.y, w2.z, w2.w};
#pragma unroll
        for (int e = 0; e < 8; ++e) {
            short hh, ll;
            split_bf16(v[e], hh, ll);
            h[e] = hh; l[e] = ll;
        }
    };

    float4 a4[4], b4[4];
    auto LOADAB = [&](int kb) {
        const float* Ap = A + (size_t)(m0 + srow) * K + kb + ks;
        const float* Bp = B + (size_t)(n0 + srow) * K + kb + ks;
#pragma unroll
        for (int g = 0; g < 4; ++g) a4[g] = ((const float4*)Ap)[g];
#pragma unroll
        for (int g = 0; g < 4; ++g) b4[g] = ((const float4*)Bp)[g];
    };

    const int o0 = ((smt * 4 + sq0) * 16 + slm) * 8;
    const int o1 = ((smt * 4 + sq0 + 1) * 16 + slm) * 8;

    // convert a4/b4 (data of step s) -> LDS buffer s&1
    auto STAGE = [&](int s) {
        if (BN_A) {
            const int sel = s >> 5;               // channel within chunk
            const float m   = sel ? bnm1 : bnm0;
            const float inv = sel ? bni1 : bni0;
#pragma unroll
            for (int g = 0; g < 4; ++g) {
                a4[g].x = lrelu((a4[g].x - m) * inv);
                a4[g].y = lrelu((a4[g].y - m) * inv);
                a4[g].z = lrelu((a4[g].z - m) * inv);
                a4[g].w = lrelu((a4[g].w - m) * inv);
            }
        }
        frag ah0, al0, ah1, al1, bh0, bl0, bh1, bl1;
        cv8(a4[0], a4[1], ah0, al0);
        cv8(a4[2], a4[3], ah1, al1);
        cv8(b4[0], b4[1], bh0, bl0);
        cv8(b4[2], b4[3], bh1, bl1);
        const int pb = (s & 1) << 12;             // buffer offset (4096 shorts)
        *(frag*)&AhL[pb + o0] = ah0;  *(frag*)&AhL[pb + o1] = ah1;
        *(frag*)&AlL[pb + o0] = al0;  *(frag*)&AlL[pb + o1] = al1;
        *(frag*)&BhL[pb + o0] = bh0;  *(frag*)&BhL[pb + o1] = bh1;
        *(frag*)&BlL[pb + o0] = bl0;  *(frag*)&BlL[pb + o1] = bl1;
    };

    // MFMA for step s from LDS buffer s&1
    auto MMA = [&](int s) {
        const int pb = (s & 1) << 12;
        frag fah[4], fal[4], fbh[4], fbl[4];
#pragma unroll
        for (int t = 0; t < 4; ++t) {
            const int oa = pb + (((wm * 4 + t) * 4 + q) * 16 + lm) * 8;
            const int ob = pb + (((wn * 4 + t) * 4 + q) * 16 + lm) * 8;
            fah[t] = *(const frag*)&AhL[oa];
            fal[t] = *(const frag*)&AlL[oa];
            fbh[t] = *(const frag*)&BhL[ob];
            fbl[t] = *(const frag*)&BlL[ob];
        }
        __builtin_amdgcn_s_setprio(1);
#pragma unroll
        for (int i = 0; i < 4; ++i)
#pragma unroll
            for (int j = 0; j < 4; ++j) {
                acc[i][j] = __builtin_amdgcn_mfma_f32_16x16x32_bf16(
                    fah[i], fbh[j], acc[i][j], 0, 0, 0);
                acc[i][j] = __builtin_amdgcn_mfma_f32_16x16x32_bf16(
                    fah[i], fbl[j], acc[i][j], 0, 0, 0);
                acc[i][j] = __builtin_amdgcn_mfma_f32_16x16x32_bf16(
                    fal[i], fbh[j], acc[i][j], 0, 0, 0);
            }
        __builtin_amdgcn_s_setprio(0);
    };

    const int T = kchunk >> 5;                    // K-steps per block (>= 2)

    LOADAB(k0);                                   // step 0 data
    STAGE(0);
    LOADAB(k0 + 32);                              // step 1 data
    BAR();

#pragma unroll 1
    for (int s = 1; s < T; ++s) {
        MMA(s - 1);                               // consume buf[(s-1)&1]
        STAGE(s);                                 // fill buf[s&1]
        if (s + 1 < T) LOADAB(k0 + (s + 1) * 32); // prefetch step s+1
        BAR();                                    // one barrier per K-step
    }
    MMA(T - 1);

#pragma unroll
    for (int i = 0; i < 4; ++i) {
        const int m = m0 + wm * 64 + i * 16 + q * 4;
#pragma unroll
        for (int j = 0; j < 4; ++j) {
            const int n = n0 + wn * 64 + j * 16 + lm;
            float* cp = C + (size_t)m * Nh + n;
#pragma unroll
            for (int r = 0; r < 4; ++r)
                atomicAdd(cp + (size_t)r * Nh, acc[i][j][r]);
        }
    }
}

// ================= bias + leaky relu for a PAIR of buffers, in place ========
__global__ __launch_bounds__(256) void bias_lrelu2_kernel(
    float* __restrict__ bufa, const float* __restrict__ ba,
    float* __restrict__ bufb, const float* __restrict__ bb,
    int Nn, int per)
{
    const int idx = blockIdx.x * 256 + threadIdx.x;
    if (idx < per) {
        bufa[idx] = lrelu(bufa[idx] + ba[idx % Nn]);
    } else {
        const int j = idx - per;
        bufb[j] = lrelu(bufb[j] + bb[j % Nn]);
    }
}

// ================= block reduce + atomic helper =================
__device__ __forceinline__ void block_reduce_atomic(float t, float* target)
{
#pragma unroll
    for (int off = 32; off > 0; off >>= 1) t += __shfl_down(t, off, 64);
    __shared__ float lt[4];
    const int wave = threadIdx.x >> 6, lane = threadIdx.x & 63;
    if (lane == 0) lt[wave] = t;
    __syncthreads();
    if (threadIdx.x == 0) atomicAdd(target, lt[0] + lt[1] + lt[2] + lt[3]);
}

// ================= product-of-experts group posterior + kl2 =================
__global__ __launch_bounds__(256) void poe_kernel(
    const float* __restrict__ mu1, const float* __restrict__ lv1,
    float* __restrict__ gmu, float* __restrict__ glv, float* __restrict__ kl)
{
    const int l = blockIdx.x * 256 + threadIdx.x;
    float sp = 0.f, sm = 0.f;
    for (int n = 0; n < N_; ++n) {
        const float lv = lv1[(size_t)n * L_ + l];
        const float p  = expf(-lv);
        sp += p;
        sm += mu1[(size_t)n * L_ + l] * p;
    }
    const float gv = 1.f / sp;
    const float gm = sm * gv;
    const float gl = -logf(sp);
    gmu[l] = gm;
    glv[l] = gl;
    const float t = -0.5f * (1.f + gl) + 0.5f * (gm * gm + gv * gv);
    block_reduce_atomic(t, &kl[1]);
}

// ================= reparameterize + kl1 =================
__global__ __launch_bounds__(256) void reparam_kernel(
    const float* __restrict__ mu0, const float* __restrict__ lv0,
    const float* __restrict__ eps_c, const float* __restrict__ eps_s,
    const float* __restrict__ gmu, const float* __restrict__ glv,
    float* __restrict__ zc, float* __restrict__ zs, float* __restrict__ kl)
{
    const int idx = blockIdx.x * 256 + threadIdx.x;
    const int l = idx & (L_ - 1);
    const float m  = mu0[idx];
    const float lv = lv0[idx];
    zc[idx] = eps_c[idx] * expf(0.5f * lv) + m;
    zs[idx] = eps_s[idx] * expf(0.5f * glv[l]) + gmu[l];
    const float e = expf(lv);
    const float t = -0.5f * (1.f + lv) + 0.5f * (m * m + e * e);
    block_reduce_atomic(t, &kl[0]);
}

// ================= final: BN of decoder outputs + output + loss ============
__global__ __launch_bounds__(256) void final_kernel(
    const float* __restrict__ x, const float* __restrict__ oc,
    const float* __restrict__ os, const float* __restrict__ stC,
    const float* __restrict__ stS, const float* __restrict__ kl,
    float* __restrict__ out)
{
    const int idx = blockIdx.x * 256 + threadIdx.x;
    const float mc = stC[0] * IC_, qc = stC[1] * IC_;
    const float ivc = rsqrtf(qc - mc * mc + 1e-5f);
    const float ms = stS[0] * IC_, qs = stS[1] * IC_;
    const float ivs = rsqrtf(qs - ms * ms + 1e-5f);
    const float tc = lrelu((oc[idx] - mc) * ivc);
    const float ts = fmaxf((os[idx] - ms) * ivs, 0.f);
    const float o = tc * ts;
    const float d = expf(x[idx]) - expf(o);
    out[idx]            = -kl[0] + kl[1] + d * d;
    out[N_ * PIX + idx] = o;
}

// ================= host launch =================
extern "C" void kernel_launch(void* const* d_in, const int* in_sizes, int n_in,
                              void* d_out, int out_size, void* d_ws, size_t ws_size,
                              hipStream_t stream)
{
    const float* x        = (const float*)d_in[0];
    const float* eps_c    = (const float*)d_in[1];
    const float* eps_s    = (const float*)d_in[2];
    const float* enc_cw1  = (const float*)d_in[3];
    const float* enc_cb1  = (const float*)d_in[4];
    const float* enc_cw2  = (const float*)d_in[5];
    const float* enc_cb2  = (const float*)d_in[6];
    const float* enc_cw3  = (const float*)d_in[7];
    const float* enc_cb3  = (const float*)d_in[8];
    const float* enc_muW1 = (const float*)d_in[9];
    const float* enc_muB1 = (const float*)d_in[10];
    const float* enc_muW2 = (const float*)d_in[11];
    const float* enc_muB2 = (const float*)d_in[12];
    const float* enc_vaW1 = (const float*)d_in[13];
    const float* enc_vaB1 = (const float*)d_in[14];
    const float* enc_vaW2 = (const float*)d_in[15];
    const float* enc_vaB2 = (const float*)d_in[16];
    const float* dec_cw1  = (const float*)d_in[17];
    const float* dec_cb1  = (const float*)d_in[18];
    const float* dec_cw2  = (const float*)d_in[19];
    const float* dec_cb2  = (const float*)d_in[20];
    const float* dec_cw3  = (const float*)d_in[21];
    const float* dec_cb3  = (const float*)d_in[22];
    float* out = (float*)d_out;

    // ---- workspace layout (floats) ----
    float* ws   = (float*)d_ws;
    float* bufA = ws;                             // N*64*PIX
    float* bufB = bufA + (size_t)N_ * 64 * PIX;   // N*32*PIX
    float* h1   = bufB + (size_t)N_ * 32 * PIX;   // N*H
    float* h2   = h1 + N_ * H_;
    float* mu0  = h2 + N_ * H_;                   // N*L each below
    float* lv0  = mu0 + N_ * L_;
    float* mu1  = lv0 + N_ * L_;
    float* lv1  = mu1 + N_ * L_;
    float* zc   = lv1 + N_ * L_;
    float* zs   = zc + N_ * L_;
    float* oc   = zs + N_ * L_;
    float* os   = oc + N_ * L_;
    float* gmu  = os + N_ * L_;                   // L
    float* glv  = gmu + L_;                       // L
    float* stats = glv + L_;                      // 12 slots x 128
    float* kl   = stats + 12 * 128;               // 4 (2 used, pad to align)
    // pre-split conv weights (16-B aligned: float offset is multiple of 4)
    short* wsh  = (short*)(kl + 4);               // 6 layers x 18432 shorts (hi)
    short* wsl  = wsh + 6 * 18432;                // (lo)

    auto st  = [&](int s) { return stats + 128 * s; };
    auto whp = [&](int layer) { return wsh + layer * 18432; };
    auto wlp = [&](int layer) { return wsl + layer * 18432; };

    // stats + kl are contiguous: one memset
    hipMemsetAsync(stats, 0, (12 * 128 + 4) * sizeof(float), stream);

    // pre-split conv weights into MFMA fragment order (all 6 layers, 1 launch)
    wsplit6_kernel<<<dim3(72, 6), 256, 0, stream>>>(
        enc_cw2, enc_cw3, enc_cw2 + 64 * 32 * 9, enc_cw3 + 32 * 64 * 9,
        dec_cw2, dec_cw2 + 64 * 32 * 9, wsh, wsl);

    // ================== encoders ==================
    for (int i = 0; i < 2; ++i) {
        const float* cw1 = enc_cw1 + (size_t)i * 32 * 9;
        const float* cb1 = enc_cb1 + (size_t)i * 32;
        const float* cb2 = enc_cb2 + (size_t)i * 64;
        const float* cb3 = enc_cb3 + (size_t)i * 32;

        conv3x3<1, 16, false><<<N_ * 2, 256, 0, stream>>>(
            x, cw1, cb1, bufB, nullptr, st(i * 3 + 0), 32);
        conv_mfma<32, 64, true><<<N_ * 8, 256, 0, stream>>>(
            bufB, whp(i * 2), wlp(i * 2), cb2, bufA, st(i * 3 + 0), st(i * 3 + 1));
        conv_mfma<64, 32, true><<<N_ * 8, 256, 0, stream>>>(
            bufA, whp(i * 2 + 1), wlp(i * 2 + 1), cb3, bufB, st(i * 3 + 1), st(i * 3 + 2));
        // bufB = raw conv3 out; BN+lrelu fused into GEMM A staging

        const float* W1m = enc_muW1 + (size_t)i * H_ * F_;
        const float* B1m = enc_muB1 + (size_t)i * H_;
        const float* W2m = enc_muW2 + (size_t)i * L_ * H_;
        const float* B2m = enc_muB2 + (size_t)i * L_;
        const float* W1v = enc_vaW1 + (size_t)i * H_ * F_;
        const float* B1v = enc_vaB1 + (size_t)i * H_;
        const float* W2v = enc_vaW2 + (size_t)i * L_ * H_;
        const float* B2v = enc_vaB2 + (size_t)i * L_;
        float* mu_i = (i == 0) ? mu0 : mu1;
        float* lv_i = (i == 0) ? lv0 : lv1;

        // h1,h2 contiguous; mu_i,lv_i contiguous: one memset each
        hipMemsetAsync(h1, 0, (size_t)2 * N_ * H_ * sizeof(float), stream);
        gemm_mfma<true><<<dim3(8, 4, 16), 256, 0, stream>>>(
            bufB, bufB, W1m, W1v, h1, h2, F_, H_, 2048, 4, st(i * 3 + 2), 32);
        bias_lrelu2_kernel<<<(2 * N_ * H_) / 256, 256, 0, stream>>>(
            h1, B1m, h2, B1v, H_, N_ * H_);

        hipMemsetAsync(mu_i, 0, (size_t)2 * N_ * L_ * sizeof(float), stream);
        gemm_mfma<false><<<dim3(16, 4, 8), 256, 0, stream>>>(
            h1, h2, W2m, W2v, mu_i, lv_i, H_, L_, 64, 8, nullptr, 0);
        bias_lrelu2_kernel<<<(2 * N_ * L_) / 256, 256, 0, stream>>>(
            mu_i, B2m, lv_i, B2v, L_, N_ * L_);
    }

    // ================== PoE + reparam + KL ==================
    poe_kernel<<<L_ / 256, 256, 0, stream>>>(mu1, lv1, gmu, glv, kl);
    reparam_kernel<<<(N_ * L_) / 256, 256, 0, stream>>>(
        mu0, lv0, eps_c, eps_s, gmu, glv, zc, zs, kl);

    // ================== decoders ==================
    for (int i = 0; i < 2; ++i) {
        const float* cw1 = dec_cw1 + (size_t)i * 32 * 9;
        const float* cb1 = dec_cb1 + (size_t)i * 32;
        const float* cb2 = dec_cb2 + (size_t)i * 64;
        const float* cw3 = dec_cw3 + (size_t)i * 64 * 9;
        const float* cb3 = dec_cb3 + (size_t)i * 1;
        const float* zi = (i == 0) ? zc : zs;
        float* oi = (i == 0) ? oc : os;

        conv3x3<1, 16, false><<<N_ * 2, 256, 0, stream>>>(
            zi, cw1, cb1, bufB, nullptr, st(6 + i * 3 + 0), 32);
        conv_mfma<32, 64, true><<<N_ * 8, 256, 0, stream>>>(
            bufB, whp(4 + i), wlp(4 + i), cb2, bufA, st(6 + i * 3 + 0), st(6 + i * 3 + 1));
        conv3x3<64, 1, true><<<N_, 256, 0, stream>>>(
            bufA, cw3, cb3, oi, st(6 + i * 3 + 1), st(6 + i * 3 + 2), 1);
    }

    // ================== output + loss (BN of oc/os fused) ==================
    final_kernel<<<(N_ * PIX) / 256, 256, 0, stream>>>(
        x, oc, os, st(8), st(11), kl, out);
}

// Round 6
// 1457.877 us; speedup vs baseline: 1.1154x; 1.1154x over previous
//
#include <hip/hip_runtime.h>

// ---------------- problem constants ----------------
constexpr int N_   = 512;
constexpr int PIX  = 1024;    // 32*32
constexpr int L_   = 1024;
constexpr int F_   = 32768;   // 32*32*32
constexpr int H_   = 512;
constexpr float IC_ = 1.0f / (float)(512 * 1024);   // 1/(N*PIX), BN count

__device__ __forceinline__ float lrelu(float t) { return t >= 0.f ? t : 0.01f * t; }

using frag  = __attribute__((ext_vector_type(8))) short;   // 8 bf16 (4 VGPRs)
using f32x4 = __attribute__((ext_vector_type(4))) float;   // MFMA accum
using s4    = __attribute__((ext_vector_type(4))) short;   // ds_write_b64 pack

// Non-draining barrier: orders LDS (lgkmcnt) but lets register-destined
// global loads stay in flight across the barrier.
#define BAR() do {                                              \
    asm volatile("s_waitcnt lgkmcnt(0)" ::: "memory");          \
    __builtin_amdgcn_s_barrier();                               \
    asm volatile("" ::: "memory");                              \
} while (0)

// split v = hi + lo, both bf16 (truncation; lo captures the tail exactly,
// dropped lo*lo term ~2^-16 relative)
__device__ __forceinline__ void split_bf16(float v, short& hi, short& lo) {
    const unsigned b = __float_as_uint(v);
    hi = (short)(b >> 16);
    const float hf = __uint_as_float(b & 0xFFFF0000u);
    lo = (short)(__float_as_uint(v - hf) >> 16);
}

// two ds_read_b64 -> one 8-bf16 fragment (stride-72B LDS rows can't align b128)
__device__ __forceinline__ frag ld2(const short* p) {
    union { frag f; struct { unsigned long long a, b; } u; } x;
    x.u.a = *(const unsigned long long*)(p);
    x.u.b = *(const unsigned long long*)(p + 4);
    return x.f;
}

// ======== weight pre-split: OIHW fp32 -> fragment-ordered bf16 hi/lo ========
// All 6 big-conv layers in ONE launch: grid (72, 6), layer = blockIdx.y.
__global__ __launch_bounds__(256) void wsplit6_kernel(
    const float* __restrict__ w0, const float* __restrict__ w1,
    const float* __restrict__ w2, const float* __restrict__ w3,
    const float* __restrict__ w4, const float* __restrict__ w5,
    short* __restrict__ hi, short* __restrict__ lo)
{
    const int layer = blockIdx.y;
    const float* W = layer == 0 ? w0 : layer == 1 ? w1 : layer == 2 ? w2 :
                     layer == 3 ? w3 : layer == 4 ? w4 : w5;
    const int CIN  = (layer == 1 || layer == 3) ? 64 : 32;
    const int NCOT = (layer == 1 || layer == 3) ? 2 : 4;
    const int idx = blockIdx.x * 256 + threadIdx.x;       // 72*256 = 18432 exact
    const int j    = idx & 7;
    const int lane = (idx >> 3) & 63;
    const int q    = lane >> 4, lm = lane & 15;
    const int blk  = idx >> 9;
    const int cot  = blk % NCOT;
    const int rest = blk / NCOT;
    const int pos  = rest % 9;
    const int cc   = rest / 9;
    const int co = cot * 16 + lm;
    const int ci = cc * 32 + q * 8 + j;
    short h, l;
    split_bf16(W[((size_t)co * CIN + ci) * 9 + pos], h, l);
    hi[layer * 18432 + idx] = h;
    lo[layer * 18432 + idx] = l;
}

// ======== conv 3x3 SAME via implicit-GEMM MFMA (split-bf16, 3-pass) =========
// R4-proven shape: block = one image, 8 output rows (256 px), ALL Cout.
// Batch-32 staging, BN m/inv cached in LDS, non-draining BARs, weight dbuf.
template<int CIN, int COUT, bool BN_IN>
__global__ __launch_bounds__(256) void conv_mfma(
    const float* __restrict__ in, const short* __restrict__ wh,
    const short* __restrict__ wl, const float* __restrict__ bias,
    float* __restrict__ out, const float* __restrict__ stats_in,
    float* __restrict__ stats_out)
{
    constexpr int NCOT = COUT / 16;
    constexpr int NCH  = CIN / 32;
    constexpr int STR  = 36;              // shorts per staged pixel
    constexpr int PLsh = 340 * STR;       // plane: 10 rows x 34 cols
    __shared__ __align__(16) short hiL[PLsh];
    __shared__ __align__(16) short loL[PLsh];       // ~48 KB
    __shared__ float red[2 * COUT];
    __shared__ float bnm[64], bni[64];
    const int tid  = threadIdx.x;
    const int n    = blockIdx.x >> 2;
    const int y0   = (blockIdx.x & 3) << 3;
    const int lane = tid & 63;
    const int wv   = tid >> 6;
    const int lm   = lane & 15;
    const int q    = lane >> 4;

    if (tid < 2 * COUT) red[tid] = 0.f;
    if (BN_IN && tid < CIN) {
        const float m  = stats_in[tid] * IC_;
        const float qq = stats_in[CIN + tid] * IC_;
        bnm[tid] = m;
        bni[tid] = rsqrtf(qq - m * m + 1e-5f);
    }
    __syncthreads();

    f32x4 acc[NCOT][4];
#pragma unroll
    for (int t = 0; t < NCOT; ++t)
#pragma unroll
        for (int pt = 0; pt < 4; ++pt) acc[t][pt] = {0.f, 0.f, 0.f, 0.f};

    // staging coords: 340 staged px covered by tid and tid+256
    const int rs0 = tid / 34, cs0 = tid % 34;
    const int idx1 = tid + 256;
    const int rs1 = idx1 / 34, cs1 = idx1 % 34;
    const int gr0 = y0 - 1 + rs0, gc0 = cs0 - 1;
    const int gr1 = y0 - 1 + rs1, gc1 = cs1 - 1;
    const bool in1 = idx1 < 340;
    const bool ok0 = ((unsigned)gr0 < 32u) && ((unsigned)gc0 < 32u);
    const bool ok1 = in1 && ((unsigned)gr1 < 32u) && ((unsigned)gc1 < 32u);
    const int  po0 = gr0 * 32 + gc0;
    const int  po1 = gr1 * 32 + gc1;

    const float* inb = in + ((size_t)n * CIN << 10);

    // weight fragment double-buffer (static register sets — no runtime index)
    frag ahA[NCOT], alA[NCOT], ahB[NCOT], alB[NCOT];

    auto LDW = [&](frag (&dh)[NCOT], frag (&dl)[NCOT], int posAbs) {
#pragma unroll
        for (int t = 0; t < NCOT; ++t) {
            const size_t wb = (size_t)((posAbs * NCOT + t) * 512 + lane * 8);
            dh[t] = *(const frag*)&wh[wb];
            dl[t] = *(const frag*)&wl[wb];
        }
    };

    auto COMPUTE = [&](int pos, frag (&fh)[NCOT], frag (&fl)[NCOT]) {
        const int ky = pos / 3, kx = pos - ky * 3;
        __builtin_amdgcn_s_setprio(1);
#pragma unroll
        for (int pt = 0; pt < 4; ++pt) {
            const int ptile = wv * 4 + pt;
            const int row = ptile >> 1;
            const int col = ((ptile & 1) << 4) + lm;
            const int loff = ((row + ky) * 34 + col + kx) * STR + q * 8;
            const frag bh = ld2(&hiL[loff]);
            const frag bl = ld2(&loL[loff]);
#pragma unroll
            for (int t = 0; t < NCOT; ++t) {
                acc[t][pt] = __builtin_amdgcn_mfma_f32_16x16x32_bf16(
                    fh[t], bh, acc[t][pt], 0, 0, 0);
                acc[t][pt] = __builtin_amdgcn_mfma_f32_16x16x32_bf16(
                    fh[t], bl, acc[t][pt], 0, 0, 0);
                acc[t][pt] = __builtin_amdgcn_mfma_f32_16x16x32_bf16(
                    fl[t], bh, acc[t][pt], 0, 0, 0);
            }
        }
        __builtin_amdgcn_s_setprio(0);
    };

#pragma unroll 1
    for (int cc = 0; cc < NCH; ++cc) {
        if (cc) BAR();                    // previous chunk's reads done

        // prefetch pos-0 weights of this chunk; flies under the staging phase
        LDW(ahA, alA, cc * 9 + 0);

        // ---- staging: ALL 64 loads of the chunk in one batch ----
        {
            float v0r[32], v1r[32];
#pragma unroll
            for (int u = 0; u < 32; ++u) {
                const int cg = cc * 32 + u;
                v0r[u] = ok0 ? inb[((size_t)cg << 10) + po0] : 0.f;
                v1r[u] = ok1 ? inb[((size_t)cg << 10) + po1] : 0.f;
            }
#pragma unroll
            for (int u4 = 0; u4 < 32; u4 += 4) {
                s4 h0v, l0v, h1v, l1v;
#pragma unroll
                for (int e = 0; e < 4; ++e) {
                    const int ci = u4 + e;
                    const int cg = cc * 32 + ci;
                    float v0 = v0r[ci];
                    if (BN_IN && ok0) v0 = lrelu((v0 - bnm[cg]) * bni[cg]);
                    short h, l;
                    split_bf16(v0, h, l);
                    h0v[e] = h; l0v[e] = l;
                    float v1 = v1r[ci];
                    if (BN_IN && ok1) v1 = lrelu((v1 - bnm[cg]) * bni[cg]);
                    short h1, l1;
                    split_bf16(v1, h1, l1);
                    h1v[e] = h1; l1v[e] = l1;
                }
                *(s4*)&hiL[tid * STR + u4] = h0v;
                *(s4*)&loL[tid * STR + u4] = l0v;
                if (in1) {
                    *(s4*)&hiL[idx1 * STR + u4] = h1v;
                    *(s4*)&loL[idx1 * STR + u4] = l1v;
                }
            }
        }
        BAR();

        // ---- 9 positions, weights double-buffered (A holds pos, B pos+1) ---
#pragma unroll 1
        for (int pos = 0; pos < 8; pos += 2) {
            LDW(ahB, alB, cc * 9 + pos + 1);   // prefetch pos+1
            COMPUTE(pos, ahA, alA);            // consume pos (already landed)
            LDW(ahA, alA, cc * 9 + pos + 2);   // prefetch pos+2 (max 8)
            COMPUTE(pos + 1, ahB, alB);        // consume pos+1
        }
        COMPUTE(8, ahA, alA);                  // tail: pos 8
    }

    // ---- epilogue: bias, store raw, per-channel stats ----
    // C/D: col(n=px)=lane&15, row(m=co within tile)=q*4+reg
    float* ob = out + ((size_t)n * COUT << 10);
#pragma unroll
    for (int t = 0; t < NCOT; ++t) {
#pragma unroll
        for (int r = 0; r < 4; ++r) {
            const int co = t * 16 + q * 4 + r;
            const float b = bias[co];
            float s = 0.f, sq = 0.f;
#pragma unroll
            for (int pt = 0; pt < 4; ++pt) {
                const float v = acc[t][pt][r] + b;
                ob[((size_t)co << 10) + (y0 << 5) + ((wv * 4 + pt) << 4) + lm] = v;
                s += v; sq += v * v;
            }
#pragma unroll
            for (int off = 8; off > 0; off >>= 1) {
                s  += __shfl_down(s, off, 64);
                sq += __shfl_down(sq, off, 64);
            }
            if (lm == 0) {
                atomicAdd(&red[co], s);
                atomicAdd(&red[COUT + co], sq);
            }
        }
    }
    __syncthreads();
    if (tid < 2 * COUT) atomicAdd(&stats_out[tid], red[tid]);
}

// ================= conv 3x3 VALU — conv1 & dec-conv3 only ===
template<int CIN, int COPB, bool BN_IN>
__global__ __launch_bounds__(256) void conv3x3(
    const float* __restrict__ in, const float* __restrict__ w,
    const float* __restrict__ bias, float* __restrict__ out,
    const float* __restrict__ stats_in, float* __restrict__ stats_out,
    int Cout)
{
    constexpr int CT = (CIN < 4) ? CIN : 4;
    __shared__ float tile[CT * PIX];
    __shared__ float red[2 * COPB];
    const int groups = Cout / COPB;
    const int n   = blockIdx.x / groups;
    const int co0 = (blockIdx.x % groups) * COPB;
    const int tid = threadIdx.x;
    const int x   = tid & 31;
    const int y0  = (tid >> 5) * 4;

    float acc[COPB][4];
#pragma unroll
    for (int c = 0; c < COPB; ++c)
#pragma unroll
        for (int j = 0; j < 4; ++j) acc[c][j] = 0.f;

    const float* inbase = in + (size_t)n * CIN * PIX;

#pragma unroll 1
    for (int s0 = 0; s0 < CIN; s0 += CT) {
        __syncthreads();
#pragma unroll
        for (int s = 0; s < CT; ++s) {
            float4 v = ((const float4*)(inbase + (size_t)(s0 + s) * PIX))[tid];
            if (BN_IN) {
                const int c = s0 + s;
                const float m   = stats_in[c] * IC_;
                const float q   = stats_in[CIN + c] * IC_;
                const float inv = rsqrtf(q - m * m + 1e-5f);
                v.x = lrelu((v.x - m) * inv);
                v.y = lrelu((v.y - m) * inv);
                v.z = lrelu((v.z - m) * inv);
                v.w = lrelu((v.w - m) * inv);
            }
            ((float4*)tile)[s * 256 + tid] = v;
        }
        __syncthreads();
#pragma unroll 2
        for (int s = 0; s < CT; ++s) {
            const int ci = s0 + s;
            const float* tp = tile + s * PIX;
            float r[6][3];
#pragma unroll
            for (int ry = 0; ry < 6; ++ry) {
                const int yy = y0 + ry - 1;
                const bool yok = (unsigned)yy < 32u;
#pragma unroll
                for (int cx = 0; cx < 3; ++cx) {
                    const int xx = x + cx - 1;
                    const bool ok = yok && ((unsigned)xx < 32u);
                    r[ry][cx] = ok ? tp[yy * 32 + xx] : 0.f;
                }
            }
#pragma unroll
            for (int c = 0; c < COPB; ++c) {
                const float* wp = w + ((size_t)(co0 + c) * CIN + ci) * 9;
#pragma unroll
                for (int ky = 0; ky < 3; ++ky)
#pragma unroll
                    for (int kx = 0; kx < 3; ++kx) {
                        const float wv = wp[ky * 3 + kx];
#pragma unroll
                        for (int j = 0; j < 4; ++j)
                            acc[c][j] += r[ky + j][kx] * wv;
                    }
            }
        }
    }

    if (tid < 2 * COPB) red[tid] = 0.f;
    __syncthreads();
#pragma unroll
    for (int c = 0; c < COPB; ++c) {
        const float b = bias[co0 + c];
        float* ob = out + (((size_t)n * Cout + co0 + c) << 10);
        float s = 0.f, q = 0.f;
#pragma unroll
        for (int j = 0; j < 4; ++j) {
            const float v = acc[c][j] + b;
            ob[(y0 + j) * 32 + x] = v;
            s += v; q += v * v;
        }
#pragma unroll
        for (int off = 32; off > 0; off >>= 1) {
            s += __shfl_down(s, off, 64);
            q += __shfl_down(q, off, 64);
        }
        if ((tid & 63) == 0) {
            atomicAdd(&red[c], s);
            atomicAdd(&red[COPB + c], q);
        }
    }
    __syncthreads();
    if (tid < COPB)
        atomicAdd(&stats_out[co0 + tid], red[tid]);
    else if (tid < 2 * COPB)
        atomicAdd(&stats_out[Cout + co0 + tid - COPB], red[tid]);
}

// ======== split-bf16 MFMA GEMM: C += A(MxK) * B(NxK)^T =====
// LDS double-buffered, ONE non-draining barrier per K-step (R5-proven).
// MODE 0: raw A. MODE 1: BN+lrelu on A (kchunk=2048 -> block-uniform stats).
// MODE 2: bias+lrelu on A (bias indexed by k; per-head pointer).
template<int MODE>
__global__ __launch_bounds__(256) void gemm_mfma(
    const float* __restrict__ A0, const float* __restrict__ A1,
    const float* __restrict__ B0, const float* __restrict__ B1,
    float* __restrict__ C0, float* __restrict__ C1,
    int K, int Nh, int kchunk, int xph,
    const float* __restrict__ bnstats, int Cin,
    const float* __restrict__ ba0, const float* __restrict__ ba1)
{
    __shared__ short AhL[8192], AlL[8192], BhL[8192], BlL[8192];  // 64 KB
    const int tid  = threadIdx.x;
    const int head = blockIdx.x / xph;
    const int n0   = (blockIdx.x % xph) * 128;
    const int m0   = blockIdx.y * 128;
    const float* A = head ? A1 : A0;
    const float* B = head ? B1 : B0;
    float*       C = head ? C1 : C0;
    const float* BA = head ? ba1 : ba0;
    const int k0 = blockIdx.z * kchunk;

    const int lane = tid & 63;
    const int wv   = tid >> 6;
    const int wm   = wv & 1;
    const int wn   = wv >> 1;
    const int lm   = lane & 15;
    const int q    = lane >> 4;

    const int srow = tid >> 1;
    const int smt  = srow >> 4;
    const int slm  = srow & 15;
    const int sq0  = (tid & 1) * 2;
    const int ks   = (tid & 1) * 16;

    // block-uniform BN (MODE 1): kchunk=2048 -> channels c0, c0+1
    float bnm0 = 0.f, bni0 = 1.f, bnm1 = 0.f, bni1 = 1.f;
    if (MODE == 1) {
        const int c0 = k0 >> 10;
        bnm0 = bnstats[c0] * IC_;
        const float q0 = bnstats[Cin + c0] * IC_;
        bni0 = rsqrtf(q0 - bnm0 * bnm0 + 1e-5f);
        const int c1 = (c0 + 1 < Cin) ? c0 + 1 : c0;
        bnm1 = bnstats[c1] * IC_;
        const float q1 = bnstats[Cin + c1] * IC_;
        bni1 = rsqrtf(q1 - bnm1 * bnm1 + 1e-5f);
    }

    f32x4 acc[4][4];
#pragma unroll
    for (int i = 0; i < 4; ++i)
#pragma unroll
        for (int j = 0; j < 4; ++j) acc[i][j] = {0.f, 0.f, 0.f, 0.f};

    auto cv8 = [](float4 u, float4 w2, frag& h, frag& l) {
        const float v[8] = {u.x, u.y, u.z, u.w, w2.x, w2.y, w2.z, w2.w};
#pragma unroll
        for (int e = 0; e < 8; ++e) {
            short hh, ll;
            split_bf16(v[e], hh, ll);
            h[e] = hh; l[e] = ll;
        }
    };

    float4 a4[4], b4[4];
    auto LOADAB = [&](int kb) {
        const float* Ap = A + (size_t)(m0 + srow) * K + kb + ks;
        const float* Bp = B + (size_t)(n0 + srow) * K + kb + ks;
#pragma unroll
        for (int g = 0; g < 4; ++g) a4[g] = ((const float4*)Ap)[g];
#pragma unroll
        for (int g = 0; g < 4; ++g) b4[g] = ((const float4*)Bp)[g];
    };

    const int o0 = ((smt * 4 + sq0) * 16 + slm) * 8;
    const int o1 = ((smt * 4 + sq0 + 1) * 16 + slm) * 8;

    // convert a4/b4 (data of step s) -> LDS buffer s&1
    auto STAGE = [&](int s) {
        if (MODE == 1) {
            const int sel = s >> 5;               // channel within chunk
            const float m   = sel ? bnm1 : bnm0;
            const float inv = sel ? bni1 : bni0;
#pragma unroll
            for (int g = 0; g < 4; ++g) {
                a4[g].x = lrelu((a4[g].x - m) * inv);
                a4[g].y = lrelu((a4[g].y - m) * inv);
                a4[g].z = lrelu((a4[g].z - m) * inv);
                a4[g].w = lrelu((a4[g].w - m) * inv);
            }
        }
        if (MODE == 2) {
            const float* bp = BA + k0 + s * 32 + ks;
#pragma unroll
            for (int g = 0; g < 4; ++g) {
                const float4 bv = ((const float4*)bp)[g];
                a4[g].x = lrelu(a4[g].x + bv.x);
                a4[g].y = lrelu(a4[g].y + bv.y);
                a4[g].z = lrelu(a4[g].z + bv.z);
                a4[g].w = lrelu(a4[g].w + bv.w);
            }
        }
        frag ah0, al0, ah1, al1, bh0, bl0, bh1, bl1;
        cv8(a4[0], a4[1], ah0, al0);
        cv8(a4[2], a4[3], ah1, al1);
        cv8(b4[0], b4[1], bh0, bl0);
        cv8(b4[2], b4[3], bh1, bl1);
        const int pb = (s & 1) << 12;             // buffer offset (4096 shorts)
        *(frag*)&AhL[pb + o0] = ah0;  *(frag*)&AhL[pb + o1] = ah1;
        *(frag*)&AlL[pb + o0] = al0;  *(frag*)&AlL[pb + o1] = al1;
        *(frag*)&BhL[pb + o0] = bh0;  *(frag*)&BhL[pb + o1] = bh1;
        *(frag*)&BlL[pb + o0] = bl0;  *(frag*)&BlL[pb + o1] = bl1;
    };

    // MFMA for step s from LDS buffer s&1
    auto MMA = [&](int s) {
        const int pb = (s & 1) << 12;
        frag fah[4], fal[4], fbh[4], fbl[4];
#pragma unroll
        for (int t = 0; t < 4; ++t) {
            const int oa = pb + (((wm * 4 + t) * 4 + q) * 16 + lm) * 8;
            const int ob = pb + (((wn * 4 + t) * 4 + q) * 16 + lm) * 8;
            fah[t] = *(const frag*)&AhL[oa];
            fal[t] = *(const frag*)&AlL[oa];
            fbh[t] = *(const frag*)&BhL[ob];
            fbl[t] = *(const frag*)&BlL[ob];
        }
        __builtin_amdgcn_s_setprio(1);
#pragma unroll
        for (int i = 0; i < 4; ++i)
#pragma unroll
            for (int j = 0; j < 4; ++j) {
                acc[i][j] = __builtin_amdgcn_mfma_f32_16x16x32_bf16(
                    fah[i], fbh[j], acc[i][j], 0, 0, 0);
                acc[i][j] = __builtin_amdgcn_mfma_f32_16x16x32_bf16(
                    fah[i], fbl[j], acc[i][j], 0, 0, 0);
                acc[i][j] = __builtin_amdgcn_mfma_f32_16x16x32_bf16(
                    fal[i], fbh[j], acc[i][j], 0, 0, 0);
            }
        __builtin_amdgcn_s_setprio(0);
    };

    const int T = kchunk >> 5;                    // K-steps per block (>= 2)

    LOADAB(k0);                                   // step 0 data
    STAGE(0);
    LOADAB(k0 + 32);                              // step 1 data
    BAR();

#pragma unroll 1
    for (int s = 1; s < T; ++s) {
        MMA(s - 1);                               // consume buf[(s-1)&1]
        STAGE(s);                                 // fill buf[s&1]
        if (s + 1 < T) LOADAB(k0 + (s + 1) * 32); // prefetch step s+1
        BAR();                                    // one barrier per K-step
    }
    MMA(T - 1);

#pragma unroll
    for (int i = 0; i < 4; ++i) {
        const int m = m0 + wm * 64 + i * 16 + q * 4;
#pragma unroll
        for (int j = 0; j < 4; ++j) {
            const int n = n0 + wn * 64 + j * 16 + lm;
            float* cp = C + (size_t)m * Nh + n;
#pragma unroll
            for (int r = 0; r < 4; ++r)
                atomicAdd(cp + (size_t)r * Nh, acc[i][j][r]);
        }
    }
}

// ================= block reduce + atomic helper =================
__device__ __forceinline__ void block_reduce_atomic(float t, float* target)
{
#pragma unroll
    for (int off = 32; off > 0; off >>= 1) t += __shfl_down(t, off, 64);
    __shared__ float lt[4];
    const int wave = threadIdx.x >> 6, lane = threadIdx.x & 63;
    if (lane == 0) lt[wave] = t;
    __syncthreads();
    if (threadIdx.x == 0) atomicAdd(target, lt[0] + lt[1] + lt[2] + lt[3]);
}

// ===== product-of-experts group posterior + kl2 (bias+lrelu fused in) =====
__global__ __launch_bounds__(256) void poe_kernel(
    const float* __restrict__ mu1, const float* __restrict__ lv1,
    const float* __restrict__ bmu, const float* __restrict__ blv,
    float* __restrict__ gmu, float* __restrict__ glv, float* __restrict__ kl)
{
    const int l = blockIdx.x * 256 + threadIdx.x;
    const float bm = bmu[l], bl = blv[l];
    float sp = 0.f, sm = 0.f;
    for (int n = 0; n < N_; ++n) {
        const float lv = lrelu(lv1[(size_t)n * L_ + l] + bl);
        const float p  = expf(-lv);
        sp += p;
        sm += lrelu(mu1[(size_t)n * L_ + l] + bm) * p;
    }
    const float gv = 1.f / sp;
    const float gm = sm * gv;
    const float gl = -logf(sp);
    gmu[l] = gm;
    glv[l] = gl;
    const float t = -0.5f * (1.f + gl) + 0.5f * (gm * gm + gv * gv);
    block_reduce_atomic(t, &kl[1]);
}

// ============ reparameterize + kl1 (bias+lrelu fused in) ============
__global__ __launch_bounds__(256) void reparam_kernel(
    const float* __restrict__ mu0, const float* __restrict__ lv0,
    const float* __restrict__ bmu, const float* __restrict__ blv,
    const float* __restrict__ eps_c, const float* __restrict__ eps_s,
    const float* __restrict__ gmu, const float* __restrict__ glv,
    float* __restrict__ zc, float* __restrict__ zs, float* __restrict__ kl)
{
    const int idx = blockIdx.x * 256 + threadIdx.x;
    const int l = idx & (L_ - 1);
    const float m  = lrelu(mu0[idx] + bmu[l]);
    const float lv = lrelu(lv0[idx] + blv[l]);
    zc[idx] = eps_c[idx] * expf(0.5f * lv) + m;
    zs[idx] = eps_s[idx] * expf(0.5f * glv[l]) + gmu[l];
    const float e = expf(lv);
    const float t = -0.5f * (1.f + lv) + 0.5f * (m * m + e * e);
    block_reduce_atomic(t, &kl[0]);
}

// ================= final: BN of decoder outputs + output + loss ============
__global__ __launch_bounds__(256) void final_kernel(
    const float* __restrict__ x, const float* __restrict__ oc,
    const float* __restrict__ os, const float* __restrict__ stC,
    const float* __restrict__ stS, const float* __restrict__ kl,
    float* __restrict__ out)
{
    const int idx = blockIdx.x * 256 + threadIdx.x;
    const float mc = stC[0] * IC_, qc = stC[1] * IC_;
    const float ivc = rsqrtf(qc - mc * mc + 1e-5f);
    const float ms = stS[0] * IC_, qs = stS[1] * IC_;
    const float ivs = rsqrtf(qs - ms * ms + 1e-5f);
    const float tc = lrelu((oc[idx] - mc) * ivc);
    const float ts = fmaxf((os[idx] - ms) * ivs, 0.f);
    const float o = tc * ts;
    const float d = expf(x[idx]) - expf(o);
    out[idx]            = -kl[0] + kl[1] + d * d;
    out[N_ * PIX + idx] = o;
}

// ================= host launch =================
extern "C" void kernel_launch(void* const* d_in, const int* in_sizes, int n_in,
                              void* d_out, int out_size, void* d_ws, size_t ws_size,
                              hipStream_t stream)
{
    const float* x        = (const float*)d_in[0];
    const float* eps_c    = (const float*)d_in[1];
    const float* eps_s    = (const float*)d_in[2];
    const float* enc_cw1  = (const float*)d_in[3];
    const float* enc_cb1  = (const float*)d_in[4];
    const float* enc_cw2  = (const float*)d_in[5];
    const float* enc_cb2  = (const float*)d_in[6];
    const float* enc_cw3  = (const float*)d_in[7];
    const float* enc_cb3  = (const float*)d_in[8];
    const float* enc_muW1 = (const float*)d_in[9];
    const float* enc_muB1 = (const float*)d_in[10];
    const float* enc_muW2 = (const float*)d_in[11];
    const float* enc_muB2 = (const float*)d_in[12];
    const float* enc_vaW1 = (const float*)d_in[13];
    const float* enc_vaB1 = (const float*)d_in[14];
    const float* enc_vaW2 = (const float*)d_in[15];
    const float* enc_vaB2 = (const float*)d_in[16];
    const float* dec_cw1  = (const float*)d_in[17];
    const float* dec_cb1  = (const float*)d_in[18];
    const float* dec_cw2  = (const float*)d_in[19];
    const float* dec_cb2  = (const float*)d_in[20];
    const float* dec_cw3  = (const float*)d_in[21];
    const float* dec_cb3  = (const float*)d_in[22];
    float* out = (float*)d_out;

    // ---- workspace layout (floats) ----
    float* ws   = (float*)d_ws;
    float* bufA = ws;                             // N*64*PIX
    float* bufB = bufA + (size_t)N_ * 64 * PIX;   // N*32*PIX
    float* h1   = bufB + (size_t)N_ * 32 * PIX;   // N*H
    float* h2   = h1 + N_ * H_;
    float* mu0  = h2 + N_ * H_;                   // N*L each below
    float* lv0  = mu0 + N_ * L_;
    float* mu1  = lv0 + N_ * L_;
    float* lv1  = mu1 + N_ * L_;
    float* zc   = lv1 + N_ * L_;
    float* zs   = zc + N_ * L_;
    float* oc   = zs + N_ * L_;
    float* os   = oc + N_ * L_;
    float* gmu  = os + N_ * L_;                   // L
    float* glv  = gmu + L_;                       // L
    float* stats = glv + L_;                      // 12 slots x 128
    float* kl   = stats + 12 * 128;               // 4 (2 used, pad to align)
    // pre-split conv weights (16-B aligned: float offset is multiple of 4)
    short* wsh  = (short*)(kl + 4);               // 6 layers x 18432 shorts (hi)
    short* wsl  = wsh + 6 * 18432;                // (lo)

    auto st  = [&](int s) { return stats + 128 * s; };
    auto whp = [&](int layer) { return wsh + layer * 18432; };
    auto wlp = [&](int layer) { return wsl + layer * 18432; };

    // stats + kl are contiguous: one memset
    hipMemsetAsync(stats, 0, (12 * 128 + 4) * sizeof(float), stream);

    // pre-split conv weights into MFMA fragment order (all 6 layers, 1 launch)
    wsplit6_kernel<<<dim3(72, 6), 256, 0, stream>>>(
        enc_cw2, enc_cw3, enc_cw2 + 64 * 32 * 9, enc_cw3 + 32 * 64 * 9,
        dec_cw2, dec_cw2 + 64 * 32 * 9, wsh, wsl);

    // ================== encoders ==================
    for (int i = 0; i < 2; ++i) {
        const float* cw1 = enc_cw1 + (size_t)i * 32 * 9;
        const float* cb1 = enc_cb1 + (size_t)i * 32;
        const float* cb2 = enc_cb2 + (size_t)i * 64;
        const float* cb3 = enc_cb3 + (size_t)i * 32;

        conv3x3<1, 16, false><<<N_ * 2, 256, 0, stream>>>(
            x, cw1, cb1, bufB, nullptr, st(i * 3 + 0), 32);
        conv_mfma<32, 64, true><<<N_ * 4, 256, 0, stream>>>(
            bufB, whp(i * 2), wlp(i * 2), cb2, bufA, st(i * 3 + 0), st(i * 3 + 1));
        conv_mfma<64, 32, true><<<N_ * 4, 256, 0, stream>>>(
            bufA, whp(i * 2 + 1), wlp(i * 2 + 1), cb3, bufB, st(i * 3 + 1), st(i * 3 + 2));
        // bufB = raw conv3 out; BN+lrelu fused into GEMM A staging

        const float* W1m = enc_muW1 + (size_t)i * H_ * F_;
        const float* B1m = enc_muB1 + (size_t)i * H_;
        const float* W2m = enc_muW2 + (size_t)i * L_ * H_;
        const float* W1v = enc_vaW1 + (size_t)i * H_ * F_;
        const float* B1v = enc_vaB1 + (size_t)i * H_;
        const float* W2v = enc_vaW2 + (size_t)i * L_ * H_;
        float* mu_i = (i == 0) ? mu0 : mu1;
        float* lv_i = (i == 0) ? lv0 : lv1;

        // h1,h2 contiguous; mu_i,lv_i contiguous: one memset each
        hipMemsetAsync(h1, 0, (size_t)2 * N_ * H_ * sizeof(float), stream);
        gemm_mfma<1><<<dim3(8, 4, 16), 256, 0, stream>>>(
            bufB, bufB, W1m, W1v, h1, h2, F_, H_, 2048, 4,
            st(i * 3 + 2), 32, nullptr, nullptr);

        // h bias+lrelu fused into W2-GEMM A-staging (MODE 2)
        hipMemsetAsync(mu_i, 0, (size_t)2 * N_ * L_ * sizeof(float), stream);
        gemm_mfma<2><<<dim3(16, 4, 4), 256, 0, stream>>>(
            h1, h2, W2m, W2v, mu_i, lv_i, H_, L_, 128, 8,
            nullptr, 0, B1m, B1v);
        // mu_i/lv_i left raw (+bias+lrelu applied by consumers below)
    }

    // ======= PoE + reparam + KL (encoder-head biases fused in) =======
    poe_kernel<<<L_ / 256, 256, 0, stream>>>(
        mu1, lv1, enc_muB2 + L_, enc_vaB2 + L_, gmu, glv, kl);
    reparam_kernel<<<(N_ * L_) / 256, 256, 0, stream>>>(
        mu0, lv0, enc_muB2, enc_vaB2, eps_c, eps_s, gmu, glv, zc, zs, kl);

    // ================== decoders ==================
    for (int i = 0; i < 2; ++i) {
        const float* cw1 = dec_cw1 + (size_t)i * 32 * 9;
        const float* cb1 = dec_cb1 + (size_t)i * 32;
        const float* cb2 = dec_cb2 + (size_t)i * 64;
        const float* cw3 = dec_cw3 + (size_t)i * 64 * 9;
        const float* cb3 = dec_cb3 + (size_t)i * 1;
        const float* zi = (i == 0) ? zc : zs;
        float* oi = (i == 0) ? oc : os;

        conv3x3<1, 16, false><<<N_ * 2, 256, 0, stream>>>(
            zi, cw1, cb1, bufB, nullptr, st(6 + i * 3 + 0), 32);
        conv_mfma<32, 64, true><<<N_ * 4, 256, 0, stream>>>(
            bufB, whp(4 + i), wlp(4 + i), cb2, bufA, st(6 + i * 3 + 0), st(6 + i * 3 + 1));
        conv3x3<64, 1, true><<<N_, 256, 0, stream>>>(
            bufA, cw3, cb3, oi, st(6 + i * 3 + 1), st(6 + i * 3 + 2), 1);
    }

    // ================== output + loss (BN of oc/os fused) ==================
    final_kernel<<<(N_ * PIX) / 256, 256, 0, stream>>>(
        x, oc, os, st(8), st(11), kl, out);
}

// Round 7
// 1365.292 us; speedup vs baseline: 1.1910x; 1.0678x over previous
//
#include <hip/hip_runtime.h>

// ---------------- problem constants ----------------
constexpr int N_   = 512;
constexpr int PIX  = 1024;    // 32*32
constexpr int L_   = 1024;
constexpr int F_   = 32768;   // 32*32*32
constexpr int H_   = 512;
constexpr float IC_ = 1.0f / (float)(512 * 1024);   // 1/(N*PIX), BN count

__device__ __forceinline__ float lrelu(float t) { return t >= 0.f ? t : 0.01f * t; }

using frag  = __attribute__((ext_vector_type(8))) short;   // 8 bf16 (4 VGPRs)
using f32x4 = __attribute__((ext_vector_type(4))) float;   // MFMA accum
using s4    = __attribute__((ext_vector_type(4))) short;   // ds_write_b64 pack

// Non-draining barrier: orders LDS (lgkmcnt) but lets register-destined
// global loads stay in flight across the barrier.
#define BAR() do {                                              \
    asm volatile("s_waitcnt lgkmcnt(0)" ::: "memory");          \
    __builtin_amdgcn_s_barrier();                               \
    asm volatile("" ::: "memory");                              \
} while (0)

// split v = hi + lo, both bf16 (truncation; lo captures the tail exactly,
// dropped lo*lo term ~2^-16 relative)
__device__ __forceinline__ void split_bf16(float v, short& hi, short& lo) {
    const unsigned b = __float_as_uint(v);
    hi = (short)(b >> 16);
    const float hf = __uint_as_float(b & 0xFFFF0000u);
    lo = (short)(__float_as_uint(v - hf) >> 16);
}

// two ds_read_b64 -> one 8-bf16 fragment (stride-72B LDS rows can't align b128)
__device__ __forceinline__ frag ld2(const short* p) {
    union { frag f; struct { unsigned long long a, b; } u; } x;
    x.u.a = *(const unsigned long long*)(p);
    x.u.b = *(const unsigned long long*)(p + 4);
    return x.f;
}

// ======== weight pre-split: OIHW fp32 -> fragment-ordered bf16 hi/lo ========
// All 6 big-conv layers in ONE launch: grid (72, 6), layer = blockIdx.y.
__global__ __launch_bounds__(256) void wsplit6_kernel(
    const float* __restrict__ w0, const float* __restrict__ w1,
    const float* __restrict__ w2, const float* __restrict__ w3,
    const float* __restrict__ w4, const float* __restrict__ w5,
    short* __restrict__ hi, short* __restrict__ lo)
{
    const int layer = blockIdx.y;
    const float* W = layer == 0 ? w0 : layer == 1 ? w1 : layer == 2 ? w2 :
                     layer == 3 ? w3 : layer == 4 ? w4 : w5;
    const int CIN  = (layer == 1 || layer == 3) ? 64 : 32;
    const int NCOT = (layer == 1 || layer == 3) ? 2 : 4;
    const int idx = blockIdx.x * 256 + threadIdx.x;       // 72*256 = 18432 exact
    const int j    = idx & 7;
    const int lane = (idx >> 3) & 63;
    const int q    = lane >> 4, lm = lane & 15;
    const int blk  = idx >> 9;
    const int cot  = blk % NCOT;
    const int rest = blk / NCOT;
    const int pos  = rest % 9;
    const int cc   = rest / 9;
    const int co = cot * 16 + lm;
    const int ci = cc * 32 + q * 8 + j;
    short h, l;
    split_bf16(W[((size_t)co * CIN + ci) * 9 + pos], h, l);
    hi[layer * 18432 + idx] = h;
    lo[layer * 18432 + idx] = l;
}

// ======== conv 3x3 SAME via implicit-GEMM MFMA (split-bf16, 3-pass) =========
// Round-7: 8-wave (512 thr) blocks, cot-split. Block = one image, 8 output
// rows, ALL Cout. Wave (pgrp = wv&3, cotg = wv>>2) owns ptiles pgrp*4..+3
// x cots cotg*NCOT2..+NCOT2-1. Per-thread state halves vs 4-wave version:
// acc 32, frag dbuf 32, staging single-coverage batch-16 -> ~4 waves/SIMD.
template<int CIN, int COUT, bool BN_IN>
__global__ __launch_bounds__(512) void conv_mfma(
    const float* __restrict__ in, const short* __restrict__ wh,
    const short* __restrict__ wl, const float* __restrict__ bias,
    float* __restrict__ out, const float* __restrict__ stats_in,
    float* __restrict__ stats_out)
{
    constexpr int NCOT  = COUT / 16;
    constexpr int NCOT2 = NCOT / 2;       // cots per wave
    constexpr int NCH   = CIN / 32;
    constexpr int STR  = 36;              // shorts per staged pixel
    constexpr int PLsh = 340 * STR;       // plane: 10 rows x 34 cols
    __shared__ __align__(16) short hiL[PLsh];
    __shared__ __align__(16) short loL[PLsh];       // ~48 KB
    __shared__ float red[2 * COUT];
    __shared__ float bnm[64], bni[64];
    const int tid  = threadIdx.x;
    const int n    = blockIdx.x >> 2;
    const int y0   = (blockIdx.x & 3) << 3;
    const int lane = tid & 63;
    const int wv   = tid >> 6;            // 0..7
    const int pgrp = wv & 3;              // ptile quarter
    const int cotg = wv >> 2;             // cot half
    const int lm   = lane & 15;
    const int q    = lane >> 4;

    if (tid < 2 * COUT) red[tid] = 0.f;
    if (BN_IN && tid < CIN) {
        const float m  = stats_in[tid] * IC_;
        const float qq = stats_in[CIN + tid] * IC_;
        bnm[tid] = m;
        bni[tid] = rsqrtf(qq - m * m + 1e-5f);
    }
    __syncthreads();

    f32x4 acc[NCOT2][4];
#pragma unroll
    for (int t = 0; t < NCOT2; ++t)
#pragma unroll
        for (int pt = 0; pt < 4; ++pt) acc[t][pt] = {0.f, 0.f, 0.f, 0.f};

    // staging coords: 340 staged px, one per thread (tid < 340)
    const int rs0 = tid / 34, cs0 = tid % 34;
    const int gr0 = y0 - 1 + rs0, gc0 = cs0 - 1;
    const bool act = tid < 340;
    const bool ok0 = act && ((unsigned)gr0 < 32u) && ((unsigned)gc0 < 32u);
    const int  po0 = gr0 * 32 + gc0;

    const float* inb = in + ((size_t)n * CIN << 10);

    // weight fragment double-buffer (static register sets — no runtime index)
    frag ahA[NCOT2], alA[NCOT2], ahB[NCOT2], alB[NCOT2];

    auto LDW = [&](frag (&dh)[NCOT2], frag (&dl)[NCOT2], int posAbs) {
#pragma unroll
        for (int t = 0; t < NCOT2; ++t) {
            const int cot = cotg * NCOT2 + t;
            const size_t wb = (size_t)((posAbs * NCOT + cot) * 512 + lane * 8);
            dh[t] = *(const frag*)&wh[wb];
            dl[t] = *(const frag*)&wl[wb];
        }
    };

    auto COMPUTE = [&](int pos, frag (&fh)[NCOT2], frag (&fl)[NCOT2]) {
        const int ky = pos / 3, kx = pos - ky * 3;
        __builtin_amdgcn_s_setprio(1);
#pragma unroll
        for (int pt = 0; pt < 4; ++pt) {
            const int ptile = pgrp * 4 + pt;
            const int row = ptile >> 1;
            const int col = ((ptile & 1) << 4) + lm;
            const int loff = ((row + ky) * 34 + col + kx) * STR + q * 8;
            const frag bh = ld2(&hiL[loff]);
            const frag bl = ld2(&loL[loff]);
#pragma unroll
            for (int t = 0; t < NCOT2; ++t) {
                acc[t][pt] = __builtin_amdgcn_mfma_f32_16x16x32_bf16(
                    fh[t], bh, acc[t][pt], 0, 0, 0);
                acc[t][pt] = __builtin_amdgcn_mfma_f32_16x16x32_bf16(
                    fh[t], bl, acc[t][pt], 0, 0, 0);
                acc[t][pt] = __builtin_amdgcn_mfma_f32_16x16x32_bf16(
                    fl[t], bh, acc[t][pt], 0, 0, 0);
            }
        }
        __builtin_amdgcn_s_setprio(0);
    };

#pragma unroll 1
    for (int cc = 0; cc < NCH; ++cc) {
        if (cc) BAR();                    // previous chunk's reads done

        // prefetch pos-0 weights of this chunk; flies under the staging phase
        LDW(ahA, alA, cc * 9 + 0);

        // ---- staging: one px per thread, 16-channel batches ----
#pragma unroll 1
        for (int cb = 0; cb < 32; cb += 16) {
            float v0r[16];
#pragma unroll
            for (int u = 0; u < 16; ++u) {
                const int cg = cc * 32 + cb + u;
                v0r[u] = ok0 ? inb[((size_t)cg << 10) + po0] : 0.f;
            }
            if (act) {
#pragma unroll
                for (int u4 = 0; u4 < 16; u4 += 4) {
                    s4 h0v, l0v;
#pragma unroll
                    for (int e = 0; e < 4; ++e) {
                        const int ci = cb + u4 + e;
                        const int cg = cc * 32 + ci;
                        float v0 = v0r[u4 + e];
                        if (BN_IN && ok0) v0 = lrelu((v0 - bnm[cg]) * bni[cg]);
                        short h, l;
                        split_bf16(v0, h, l);
                        h0v[e] = h; l0v[e] = l;
                    }
                    *(s4*)&hiL[tid * STR + cb + u4] = h0v;
                    *(s4*)&loL[tid * STR + cb + u4] = l0v;
                }
            }
        }
        BAR();

        // ---- 9 positions, weights double-buffered (A holds pos, B pos+1) ---
#pragma unroll 1
        for (int pos = 0; pos < 8; pos += 2) {
            LDW(ahB, alB, cc * 9 + pos + 1);   // prefetch pos+1
            COMPUTE(pos, ahA, alA);            // consume pos (already landed)
            LDW(ahA, alA, cc * 9 + pos + 2);   // prefetch pos+2 (max 8)
            COMPUTE(pos + 1, ahB, alB);        // consume pos+1
        }
        COMPUTE(8, ahA, alA);                  // tail: pos 8
    }

    // ---- epilogue: bias, store raw, per-channel stats ----
    // C/D: col(n=px)=lane&15, row(m=co within tile)=q*4+reg
    float* ob = out + ((size_t)n * COUT << 10);
#pragma unroll
    for (int t = 0; t < NCOT2; ++t) {
#pragma unroll
        for (int r = 0; r < 4; ++r) {
            const int co = (cotg * NCOT2 + t) * 16 + q * 4 + r;
            const float b = bias[co];
            float s = 0.f, sq = 0.f;
#pragma unroll
            for (int pt = 0; pt < 4; ++pt) {
                const int ptile = pgrp * 4 + pt;
                const float v = acc[t][pt][r] + b;
                ob[((size_t)co << 10) + (y0 << 5) + (ptile << 4) + lm] = v;
                s += v; sq += v * v;
            }
#pragma unroll
            for (int off = 8; off > 0; off >>= 1) {
                s  += __shfl_down(s, off, 64);
                sq += __shfl_down(sq, off, 64);
            }
            if (lm == 0) {
                atomicAdd(&red[co], s);
                atomicAdd(&red[COUT + co], sq);
            }
        }
    }
    __syncthreads();
    if (tid < 2 * COUT) atomicAdd(&stats_out[tid], red[tid]);
}

// ================= conv 3x3 VALU — conv1 & dec-conv3 only ===
template<int CIN, int COPB, bool BN_IN>
__global__ __launch_bounds__(256) void conv3x3(
    const float* __restrict__ in, const float* __restrict__ w,
    const float* __restrict__ bias, float* __restrict__ out,
    const float* __restrict__ stats_in, float* __restrict__ stats_out,
    int Cout)
{
    constexpr int CT = (CIN < 4) ? CIN : 4;
    __shared__ float tile[CT * PIX];
    __shared__ float red[2 * COPB];
    const int groups = Cout / COPB;
    const int n   = blockIdx.x / groups;
    const int co0 = (blockIdx.x % groups) * COPB;
    const int tid = threadIdx.x;
    const int x   = tid & 31;
    const int y0  = (tid >> 5) * 4;

    float acc[COPB][4];
#pragma unroll
    for (int c = 0; c < COPB; ++c)
#pragma unroll
        for (int j = 0; j < 4; ++j) acc[c][j] = 0.f;

    const float* inbase = in + (size_t)n * CIN * PIX;

#pragma unroll 1
    for (int s0 = 0; s0 < CIN; s0 += CT) {
        __syncthreads();
#pragma unroll
        for (int s = 0; s < CT; ++s) {
            float4 v = ((const float4*)(inbase + (size_t)(s0 + s) * PIX))[tid];
            if (BN_IN) {
                const int c = s0 + s;
                const float m   = stats_in[c] * IC_;
                const float q   = stats_in[CIN + c] * IC_;
                const float inv = rsqrtf(q - m * m + 1e-5f);
                v.x = lrelu((v.x - m) * inv);
                v.y = lrelu((v.y - m) * inv);
                v.z = lrelu((v.z - m) * inv);
                v.w = lrelu((v.w - m) * inv);
            }
            ((float4*)tile)[s * 256 + tid] = v;
        }
        __syncthreads();
#pragma unroll 2
        for (int s = 0; s < CT; ++s) {
            const int ci = s0 + s;
            const float* tp = tile + s * PIX;
            float r[6][3];
#pragma unroll
            for (int ry = 0; ry < 6; ++ry) {
                const int yy = y0 + ry - 1;
                const bool yok = (unsigned)yy < 32u;
#pragma unroll
                for (int cx = 0; cx < 3; ++cx) {
                    const int xx = x + cx - 1;
                    const bool ok = yok && ((unsigned)xx < 32u);
                    r[ry][cx] = ok ? tp[yy * 32 + xx] : 0.f;
                }
            }
#pragma unroll
            for (int c = 0; c < COPB; ++c) {
                const float* wp = w + ((size_t)(co0 + c) * CIN + ci) * 9;
#pragma unroll
                for (int ky = 0; ky < 3; ++ky)
#pragma unroll
                    for (int kx = 0; kx < 3; ++kx) {
                        const float wv = wp[ky * 3 + kx];
#pragma unroll
                        for (int j = 0; j < 4; ++j)
                            acc[c][j] += r[ky + j][kx] * wv;
                    }
            }
        }
    }

    if (tid < 2 * COPB) red[tid] = 0.f;
    __syncthreads();
#pragma unroll
    for (int c = 0; c < COPB; ++c) {
        const float b = bias[co0 + c];
        float* ob = out + (((size_t)n * Cout + co0 + c) << 10);
        float s = 0.f, q = 0.f;
#pragma unroll
        for (int j = 0; j < 4; ++j) {
            const float v = acc[c][j] + b;
            ob[(y0 + j) * 32 + x] = v;
            s += v; q += v * v;
        }
#pragma unroll
        for (int off = 32; off > 0; off >>= 1) {
            s += __shfl_down(s, off, 64);
            q += __shfl_down(q, off, 64);
        }
        if ((tid & 63) == 0) {
            atomicAdd(&red[c], s);
            atomicAdd(&red[COPB + c], q);
        }
    }
    __syncthreads();
    if (tid < COPB)
        atomicAdd(&stats_out[co0 + tid], red[tid]);
    else if (tid < 2 * COPB)
        atomicAdd(&stats_out[Cout + co0 + tid - COPB], red[tid]);
}

// ======== split-bf16 MFMA GEMM: C += A(MxK) * B(NxK)^T =====
// LDS double-buffered, ONE non-draining barrier per K-step (R5-proven).
// MODE 0: raw A. MODE 1: BN+lrelu on A (kchunk=2048 -> block-uniform stats).
// MODE 2: bias+lrelu on A (bias indexed by k; per-head pointer).
template<int MODE>
__global__ __launch_bounds__(256) void gemm_mfma(
    const float* __restrict__ A0, const float* __restrict__ A1,
    const float* __restrict__ B0, const float* __restrict__ B1,
    float* __restrict__ C0, float* __restrict__ C1,
    int K, int Nh, int kchunk, int xph,
    const float* __restrict__ bnstats, int Cin,
    const float* __restrict__ ba0, const float* __restrict__ ba1)
{
    __shared__ short AhL[8192], AlL[8192], BhL[8192], BlL[8192];  // 64 KB
    const int tid  = threadIdx.x;
    const int head = blockIdx.x / xph;
    const int n0   = (blockIdx.x % xph) * 128;
    const int m0   = blockIdx.y * 128;
    const float* A = head ? A1 : A0;
    const float* B = head ? B1 : B0;
    float*       C = head ? C1 : C0;
    const float* BA = head ? ba1 : ba0;
    const int k0 = blockIdx.z * kchunk;

    const int lane = tid & 63;
    const int wv   = tid >> 6;
    const int wm   = wv & 1;
    const int wn   = wv >> 1;
    const int lm   = lane & 15;
    const int q    = lane >> 4;

    const int srow = tid >> 1;
    const int smt  = srow >> 4;
    const int slm  = srow & 15;
    const int sq0  = (tid & 1) * 2;
    const int ks   = (tid & 1) * 16;

    // block-uniform BN (MODE 1): kchunk=2048 -> channels c0, c0+1
    float bnm0 = 0.f, bni0 = 1.f, bnm1 = 0.f, bni1 = 1.f;
    if (MODE == 1) {
        const int c0 = k0 >> 10;
        bnm0 = bnstats[c0] * IC_;
        const float q0 = bnstats[Cin + c0] * IC_;
        bni0 = rsqrtf(q0 - bnm0 * bnm0 + 1e-5f);
        const int c1 = (c0 + 1 < Cin) ? c0 + 1 : c0;
        bnm1 = bnstats[c1] * IC_;
        const float q1 = bnstats[Cin + c1] * IC_;
        bni1 = rsqrtf(q1 - bnm1 * bnm1 + 1e-5f);
    }

    f32x4 acc[4][4];
#pragma unroll
    for (int i = 0; i < 4; ++i)
#pragma unroll
        for (int j = 0; j < 4; ++j) acc[i][j] = {0.f, 0.f, 0.f, 0.f};

    auto cv8 = [](float4 u, float4 w2, frag& h, frag& l) {
        const float v[8] = {u.x, u.y, u.z, u.w, w2.x, w2.y, w2.z, w2.w};
#pragma unroll
        for (int e = 0; e < 8; ++e) {
            short hh, ll;
            split_bf16(v[e], hh, ll);
            h[e] = hh; l[e] = ll;
        }
    };

    float4 a4[4], b4[4];
    auto LOADAB = [&](int kb) {
        const float* Ap = A + (size_t)(m0 + srow) * K + kb + ks;
        const float* Bp = B + (size_t)(n0 + srow) * K + kb + ks;
#pragma unroll
        for (int g = 0; g < 4; ++g) a4[g] = ((const float4*)Ap)[g];
#pragma unroll
        for (int g = 0; g < 4; ++g) b4[g] = ((const float4*)Bp)[g];
    };

    const int o0 = ((smt * 4 + sq0) * 16 + slm) * 8;
    const int o1 = ((smt * 4 + sq0 + 1) * 16 + slm) * 8;

    // convert a4/b4 (data of step s) -> LDS buffer s&1
    auto STAGE = [&](int s) {
        if (MODE == 1) {
            const int sel = s >> 5;               // channel within chunk
            const float m   = sel ? bnm1 : bnm0;
            const float inv = sel ? bni1 : bni0;
#pragma unroll
            for (int g = 0; g < 4; ++g) {
                a4[g].x = lrelu((a4[g].x - m) * inv);
                a4[g].y = lrelu((a4[g].y - m) * inv);
                a4[g].z = lrelu((a4[g].z - m) * inv);
                a4[g].w = lrelu((a4[g].w - m) * inv);
            }
        }
        if (MODE == 2) {
            const float* bp = BA + k0 + s * 32 + ks;
#pragma unroll
            for (int g = 0; g < 4; ++g) {
                const float4 bv = ((const float4*)bp)[g];
                a4[g].x = lrelu(a4[g].x + bv.x);
                a4[g].y = lrelu(a4[g].y + bv.y);
                a4[g].z = lrelu(a4[g].z + bv.z);
                a4[g].w = lrelu(a4[g].w + bv.w);
            }
        }
        frag ah0, al0, ah1, al1, bh0, bl0, bh1, bl1;
        cv8(a4[0], a4[1], ah0, al0);
        cv8(a4[2], a4[3], ah1, al1);
        cv8(b4[0], b4[1], bh0, bl0);
        cv8(b4[2], b4[3], bh1, bl1);
        const int pb = (s & 1) << 12;             // buffer offset (4096 shorts)
        *(frag*)&AhL[pb + o0] = ah0;  *(frag*)&AhL[pb + o1] = ah1;
        *(frag*)&AlL[pb + o0] = al0;  *(frag*)&AlL[pb + o1] = al1;
        *(frag*)&BhL[pb + o0] = bh0;  *(frag*)&BhL[pb + o1] = bh1;
        *(frag*)&BlL[pb + o0] = bl0;  *(frag*)&BlL[pb + o1] = bl1;
    };

    // MFMA for step s from LDS buffer s&1
    auto MMA = [&](int s) {
        const int pb = (s & 1) << 12;
        frag fah[4], fal[4], fbh[4], fbl[4];
#pragma unroll
        for (int t = 0; t < 4; ++t) {
            const int oa = pb + (((wm * 4 + t) * 4 + q) * 16 + lm) * 8;
            const int ob = pb + (((wn * 4 + t) * 4 + q) * 16 + lm) * 8;
            fah[t] = *(const frag*)&AhL[oa];
            fal[t] = *(const frag*)&AlL[oa];
            fbh[t] = *(const frag*)&BhL[ob];
            fbl[t] = *(const frag*)&BlL[ob];
        }
        __builtin_amdgcn_s_setprio(1);
#pragma unroll
        for (int i = 0; i < 4; ++i)
#pragma unroll
            for (int j = 0; j < 4; ++j) {
                acc[i][j] = __builtin_amdgcn_mfma_f32_16x16x32_bf16(
                    fah[i], fbh[j], acc[i][j], 0, 0, 0);
                acc[i][j] = __builtin_amdgcn_mfma_f32_16x16x32_bf16(
                    fah[i], fbl[j], acc[i][j], 0, 0, 0);
                acc[i][j] = __builtin_amdgcn_mfma_f32_16x16x32_bf16(
                    fal[i], fbh[j], acc[i][j], 0, 0, 0);
            }
        __builtin_amdgcn_s_setprio(0);
    };

    const int T = kchunk >> 5;                    // K-steps per block (>= 2)

    LOADAB(k0);                                   // step 0 data
    STAGE(0);
    LOADAB(k0 + 32);                              // step 1 data
    BAR();

#pragma unroll 1
    for (int s = 1; s < T; ++s) {
        MMA(s - 1);                               // consume buf[(s-1)&1]
        STAGE(s);                                 // fill buf[s&1]
        if (s + 1 < T) LOADAB(k0 + (s + 1) * 32); // prefetch step s+1
        BAR();                                    // one barrier per K-step
    }
    MMA(T - 1);

#pragma unroll
    for (int i = 0; i < 4; ++i) {
        const int m = m0 + wm * 64 + i * 16 + q * 4;
#pragma unroll
        for (int j = 0; j < 4; ++j) {
            const int n = n0 + wn * 64 + j * 16 + lm;
            float* cp = C + (size_t)m * Nh + n;
#pragma unroll
            for (int r = 0; r < 4; ++r)
                atomicAdd(cp + (size_t)r * Nh, acc[i][j][r]);
        }
    }
}

// ================= block reduce + atomic helper =================
__device__ __forceinline__ void block_reduce_atomic(float t, float* target)
{
#pragma unroll
    for (int off = 32; off > 0; off >>= 1) t += __shfl_down(t, off, 64);
    __shared__ float lt[4];
    const int wave = threadIdx.x >> 6, lane = threadIdx.x & 63;
    if (lane == 0) lt[wave] = t;
    __syncthreads();
    if (threadIdx.x == 0) atomicAdd(target, lt[0] + lt[1] + lt[2] + lt[3]);
}

// ===== product-of-experts group posterior + kl2 (bias+lrelu fused in) =====
__global__ __launch_bounds__(256) void poe_kernel(
    const float* __restrict__ mu1, const float* __restrict__ lv1,
    const float* __restrict__ bmu, const float* __restrict__ blv,
    float* __restrict__ gmu, float* __restrict__ glv, float* __restrict__ kl)
{
    const int l = blockIdx.x * 256 + threadIdx.x;
    const float bm = bmu[l], bl = blv[l];
    float sp = 0.f, sm = 0.f;
    for (int n = 0; n < N_; ++n) {
        const float lv = lrelu(lv1[(size_t)n * L_ + l] + bl);
        const float p  = expf(-lv);
        sp += p;
        sm += lrelu(mu1[(size_t)n * L_ + l] + bm) * p;
    }
    const float gv = 1.f / sp;
    const float gm = sm * gv;
    const float gl = -logf(sp);
    gmu[l] = gm;
    glv[l] = gl;
    const float t = -0.5f * (1.f + gl) + 0.5f * (gm * gm + gv * gv);
    block_reduce_atomic(t, &kl[1]);
}

// ============ reparameterize + kl1 (bias+lrelu fused in) ============
__global__ __launch_bounds__(256) void reparam_kernel(
    const float* __restrict__ mu0, const float* __restrict__ lv0,
    const float* __restrict__ bmu, const float* __restrict__ blv,
    const float* __restrict__ eps_c, const float* __restrict__ eps_s,
    const float* __restrict__ gmu, const float* __restrict__ glv,
    float* __restrict__ zc, float* __restrict__ zs, float* __restrict__ kl)
{
    const int idx = blockIdx.x * 256 + threadIdx.x;
    const int l = idx & (L_ - 1);
    const float m  = lrelu(mu0[idx] + bmu[l]);
    const float lv = lrelu(lv0[idx] + blv[l]);
    zc[idx] = eps_c[idx] * expf(0.5f * lv) + m;
    zs[idx] = eps_s[idx] * expf(0.5f * glv[l]) + gmu[l];
    const float e = expf(lv);
    const float t = -0.5f * (1.f + lv) + 0.5f * (m * m + e * e);
    block_reduce_atomic(t, &kl[0]);
}

// ================= final: BN of decoder outputs + output + loss ============
__global__ __launch_bounds__(256) void final_kernel(
    const float* __restrict__ x, const float* __restrict__ oc,
    const float* __restrict__ os, const float* __restrict__ stC,
    const float* __restrict__ stS, const float* __restrict__ kl,
    float* __restrict__ out)
{
    const int idx = blockIdx.x * 256 + threadIdx.x;
    const float mc = stC[0] * IC_, qc = stC[1] * IC_;
    const float ivc = rsqrtf(qc - mc * mc + 1e-5f);
    const float ms = stS[0] * IC_, qs = stS[1] * IC_;
    const float ivs = rsqrtf(qs - ms * ms + 1e-5f);
    const float tc = lrelu((oc[idx] - mc) * ivc);
    const float ts = fmaxf((os[idx] - ms) * ivs, 0.f);
    const float o = tc * ts;
    const float d = expf(x[idx]) - expf(o);
    out[idx]            = -kl[0] + kl[1] + d * d;
    out[N_ * PIX + idx] = o;
}

// ================= host launch =================
extern "C" void kernel_launch(void* const* d_in, const int* in_sizes, int n_in,
                              void* d_out, int out_size, void* d_ws, size_t ws_size,
                              hipStream_t stream)
{
    const float* x        = (const float*)d_in[0];
    const float* eps_c    = (const float*)d_in[1];
    const float* eps_s    = (const float*)d_in[2];
    const float* enc_cw1  = (const float*)d_in[3];
    const float* enc_cb1  = (const float*)d_in[4];
    const float* enc_cw2  = (const float*)d_in[5];
    const float* enc_cb2  = (const float*)d_in[6];
    const float* enc_cw3  = (const float*)d_in[7];
    const float* enc_cb3  = (const float*)d_in[8];
    const float* enc_muW1 = (const float*)d_in[9];
    const float* enc_muB1 = (const float*)d_in[10];
    const float* enc_muW2 = (const float*)d_in[11];
    const float* enc_muB2 = (const float*)d_in[12];
    const float* enc_vaW1 = (const float*)d_in[13];
    const float* enc_vaB1 = (const float*)d_in[14];
    const float* enc_vaW2 = (const float*)d_in[15];
    const float* enc_vaB2 = (const float*)d_in[16];
    const float* dec_cw1  = (const float*)d_in[17];
    const float* dec_cb1  = (const float*)d_in[18];
    const float* dec_cw2  = (const float*)d_in[19];
    const float* dec_cb2  = (const float*)d_in[20];
    const float* dec_cw3  = (const float*)d_in[21];
    const float* dec_cb3  = (const float*)d_in[22];
    float* out = (float*)d_out;

    // ---- workspace layout (floats) ----
    float* ws   = (float*)d_ws;
    float* bufA = ws;                             // N*64*PIX
    float* bufB = bufA + (size_t)N_ * 64 * PIX;   // N*32*PIX
    float* h1   = bufB + (size_t)N_ * 32 * PIX;   // N*H
    float* h2   = h1 + N_ * H_;
    float* mu0  = h2 + N_ * H_;                   // N*L each below
    float* lv0  = mu0 + N_ * L_;
    float* mu1  = lv0 + N_ * L_;
    float* lv1  = mu1 + N_ * L_;
    float* zc   = lv1 + N_ * L_;
    float* zs   = zc + N_ * L_;
    float* oc   = zs + N_ * L_;
    float* os   = oc + N_ * L_;
    float* gmu  = os + N_ * L_;                   // L
    float* glv  = gmu + L_;                       // L
    float* stats = glv + L_;                      // 12 slots x 128
    float* kl   = stats + 12 * 128;               // 4 (2 used, pad to align)
    // pre-split conv weights (16-B aligned: float offset is multiple of 4)
    short* wsh  = (short*)(kl + 4);               // 6 layers x 18432 shorts (hi)
    short* wsl  = wsh + 6 * 18432;                // (lo)

    auto st  = [&](int s) { return stats + 128 * s; };
    auto whp = [&](int layer) { return wsh + layer * 18432; };
    auto wlp = [&](int layer) { return wsl + layer * 18432; };

    // stats + kl are contiguous: one memset
    hipMemsetAsync(stats, 0, (12 * 128 + 4) * sizeof(float), stream);

    // pre-split conv weights into MFMA fragment order (all 6 layers, 1 launch)
    wsplit6_kernel<<<dim3(72, 6), 256, 0, stream>>>(
        enc_cw2, enc_cw3, enc_cw2 + 64 * 32 * 9, enc_cw3 + 32 * 64 * 9,
        dec_cw2, dec_cw2 + 64 * 32 * 9, wsh, wsl);

    // ================== encoders ==================
    for (int i = 0; i < 2; ++i) {
        const float* cw1 = enc_cw1 + (size_t)i * 32 * 9;
        const float* cb1 = enc_cb1 + (size_t)i * 32;
        const float* cb2 = enc_cb2 + (size_t)i * 64;
        const float* cb3 = enc_cb3 + (size_t)i * 32;

        conv3x3<1, 16, false><<<N_ * 2, 256, 0, stream>>>(
            x, cw1, cb1, bufB, nullptr, st(i * 3 + 0), 32);
        conv_mfma<32, 64, true><<<N_ * 4, 512, 0, stream>>>(
            bufB, whp(i * 2), wlp(i * 2), cb2, bufA, st(i * 3 + 0), st(i * 3 + 1));
        conv_mfma<64, 32, true><<<N_ * 4, 512, 0, stream>>>(
            bufA, whp(i * 2 + 1), wlp(i * 2 + 1), cb3, bufB, st(i * 3 + 1), st(i * 3 + 2));
        // bufB = raw conv3 out; BN+lrelu fused into GEMM A staging

        const float* W1m = enc_muW1 + (size_t)i * H_ * F_;
        const float* B1m = enc_muB1 + (size_t)i * H_;
        const float* W2m = enc_muW2 + (size_t)i * L_ * H_;
        const float* W1v = enc_vaW1 + (size_t)i * H_ * F_;
        const float* B1v = enc_vaB1 + (size_t)i * H_;
        const float* W2v = enc_vaW2 + (size_t)i * L_ * H_;
        float* mu_i = (i == 0) ? mu0 : mu1;
        float* lv_i = (i == 0) ? lv0 : lv1;

        // h1,h2 contiguous; mu_i,lv_i contiguous: one memset each
        hipMemsetAsync(h1, 0, (size_t)2 * N_ * H_ * sizeof(float), stream);
        gemm_mfma<1><<<dim3(8, 4, 16), 256, 0, stream>>>(
            bufB, bufB, W1m, W1v, h1, h2, F_, H_, 2048, 4,
            st(i * 3 + 2), 32, nullptr, nullptr);

        // h bias+lrelu fused into W2-GEMM A-staging (MODE 2)
        hipMemsetAsync(mu_i, 0, (size_t)2 * N_ * L_ * sizeof(float), stream);
        gemm_mfma<2><<<dim3(16, 4, 4), 256, 0, stream>>>(
            h1, h2, W2m, W2v, mu_i, lv_i, H_, L_, 128, 8,
            nullptr, 0, B1m, B1v);
        // mu_i/lv_i left raw (+bias+lrelu applied by consumers below)
    }

    // ======= PoE + reparam + KL (encoder-head biases fused in) =======
    poe_kernel<<<L_ / 256, 256, 0, stream>>>(
        mu1, lv1, enc_muB2 + L_, enc_vaB2 + L_, gmu, glv, kl);
    reparam_kernel<<<(N_ * L_) / 256, 256, 0, stream>>>(
        mu0, lv0, enc_muB2, enc_vaB2, eps_c, eps_s, gmu, glv, zc, zs, kl);

    // ================== decoders ==================
    for (int i = 0; i < 2; ++i) {
        const float* cw1 = dec_cw1 + (size_t)i * 32 * 9;
        const float* cb1 = dec_cb1 + (size_t)i * 32;
        const float* cb2 = dec_cb2 + (size_t)i * 64;
        const float* cw3 = dec_cw3 + (size_t)i * 64 * 9;
        const float* cb3 = dec_cb3 + (size_t)i * 1;
        const float* zi = (i == 0) ? zc : zs;
        float* oi = (i == 0) ? oc : os;

        conv3x3<1, 16, false><<<N_ * 2, 256, 0, stream>>>(
            zi, cw1, cb1, bufB, nullptr, st(6 + i * 3 + 0), 32);
        conv_mfma<32, 64, true><<<N_ * 4, 512, 0, stream>>>(
            bufB, whp(4 + i), wlp(4 + i), cb2, bufA, st(6 + i * 3 + 0), st(6 + i * 3 + 1));
        conv3x3<64, 1, true><<<N_, 256, 0, stream>>>(
            bufA, cw3, cb3, oi, st(6 + i * 3 + 1), st(6 + i * 3 + 2), 1);
    }

    // ================== output + loss (BN of oc/os fused) ==================
    final_kernel<<<(N_ * PIX) / 256, 256, 0, stream>>>(
        x, oc, os, st(8), st(11), kl, out);
}